// Round 8
// baseline (402.451 us; speedup 1.0000x reference)
//
#include <hip/hip_runtime.h>
#include <hip/hip_bf16.h>

#define N_NODES 20000
#define N_EDGES 320000
#define HID 256
#define NQ 5000          // nodes per quarter (histogram privatization)
#define NCHUNK 64        // edge chunks per branch (r12: occupancy fix, verified)

typedef __attribute__((ext_vector_type(8))) short bf16x8;   // 8 bf16 = 4 VGPRs (MFMA A/B frag)
typedef __attribute__((ext_vector_type(4))) float f32x4;    // MFMA C/D frag
typedef __attribute__((ext_vector_type(8))) unsigned short us8;  // 16B row chunk

__device__ __forceinline__ float bf2f(ushort u) {
  union { unsigned int i; float f; } v; v.i = ((unsigned int)u) << 16; return v.f;
}
__device__ __forceinline__ ushort f2bf(float f) {
  union { float f; unsigned int i; } v; v.f = f;
  unsigned int r = v.i + 0x7FFFu + ((v.i >> 16) & 1u);   // RNE
  return (ushort)(r >> 16);
}

// ---------------------------------------------------------------------------
// init (zero cnt/t/P) + runtime dtype detection fused.
// flags[0]=1 -> x/weights fp32 (else bf16). flags[1]=1 -> edges int64.
// ---------------------------------------------------------------------------
__global__ void init_detect_kernel(int* cnt0, int* cnt1, float* t0, float* t1,
                                   float* P,
                                   const void* x1, const void* ei1, int* flags) {
  if (blockIdx.x == gridDim.x - 1) {
    __shared__ int cnt_wild, cnt_oddnz;
    if (threadIdx.x == 0) { cnt_wild = 0; cnt_oddnz = 0; }
    __syncthreads();
    const ushort* xu = (const ushort*)x1;
    int wild = 0;
#pragma unroll
    for (int k = 0; k < 4; k++) {
      ushort u = xu[threadIdx.x * 4 + k];
      int ex = (u >> 7) & 0xFF;
      if (ex >= 0x90) wild++;
    }
    if (wild) atomicAdd(&cnt_wild, wild);
    const int* ii = (const int*)ei1;
    if (ii[threadIdx.x * 2 + 1] != 0) atomicAdd(&cnt_oddnz, 1);
    __syncthreads();
    if (threadIdx.x == 0) {
      flags[0] = (cnt_wild > 64) ? 1 : 0;
      flags[1] = (cnt_oddnz < 8) ? 1 : 0;
    }
    return;
  }
  int i = blockIdx.x * blockDim.x + threadIdx.x;
  if (i < N_NODES) { cnt0[i] = 0; cnt1[i] = 0; t0[i] = 0.f; t1[i] = 0.f; }
  if (i < 512) P[i] = 0.f;     // pooled-sum accumulator (agg2 fused colsum)
}

// ---------------------------------------------------------------------------
// wt (r15): W[k][n] -> Wt[n][k] bf16, ONCE. Blocks 0..255 = W1 row k,
// 256..511 = W2 row k. Kills the per-gemm-block redundant transpose.
// ---------------------------------------------------------------------------
__global__ __launch_bounds__(256) void wt_kernel(
    const void* __restrict__ W1, const void* __restrict__ W2,
    ushort* __restrict__ Wt1, ushort* __restrict__ Wt2,
    const int* __restrict__ flags) {
  bool f32 = flags[0] != 0;
  int which = blockIdx.x >> 8;
  int k = blockIdx.x & 255;
  const void* W = which ? W2 : W1;
  ushort* Wt = which ? Wt2 : Wt1;
  int n = threadIdx.x;
  ushort v = f32 ? f2bf(((const float*)W)[k * 256 + n])
                 : ((const ushort*)W)[k * 256 + n];
  Wt[n * 256 + k] = v;
}

// ---------------------------------------------------------------------------
// count_rank (r17): 512-thread blocks. 1024-thr was wave-capped at 2
// blocks/CU (16 waves, 32-wave cap); 512 thr -> 8 waves, 40KB LDS x4 =
// 160KB exactly -> 4 blocks/CU, 2x latency hiding on the LDS-atomic
// phases. grid (NCHUNK*4, 2) x 512.
// ---------------------------------------------------------------------------
__global__ __launch_bounds__(512) void count_rank_kernel(
    const void* e0, const void* e1, int* cnt0, int* cnt1,
    int* rank0, int* rank1, const int* flags) {
  int b = blockIdx.y;
  const void* e = b ? e1 : e0;
  int* cnt = b ? cnt1 : cnt0;
  int* rank = b ? rank1 : rank0;
  int chunk = blockIdx.x >> 2;
  int lo = (blockIdx.x & 3) * NQ;
  int ebeg = chunk * (N_EDGES / NCHUNK);
  int eend = ebeg + (N_EDGES / NCHUNK);
  __shared__ int hist[NQ];
  __shared__ int base[NQ];
  for (int k = threadIdx.x; k < NQ; k += 512) hist[k] = 0;
  __syncthreads();
  bool w64 = flags[1] != 0;
  const int* d32 = (const int*)e + N_EDGES;
  const long long* d64 = (const long long*)e + N_EDGES;
  for (int i = ebeg + threadIdx.x; i < eend; i += 512) {
    int d = w64 ? (int)d64[i] : d32[i];
    unsigned q = (unsigned)(d - lo);
    if (q < NQ) atomicAdd(&hist[q], 1);
  }
  __syncthreads();
  for (int k = threadIdx.x; k < NQ; k += 512) {
    int h = hist[k];
    if (h) base[k] = atomicAdd(&cnt[lo + k], h);  // coalesced merge, skip zeros
    hist[k] = 0;                                  // reuse as local rank ctr
  }
  __syncthreads();
  for (int i = ebeg + threadIdx.x; i < eend; i += 512) {
    int d = w64 ? (int)d64[i] : d32[i];
    unsigned q = (unsigned)(d - lo);
    if (q < NQ) rank[i] = base[q] + atomicAdd(&hist[q], 1);
  }
}

// Exclusive scan -> CSR row_ptr, fused with dinv = rsqrt(cnt+1).
__global__ __launch_bounds__(1024) void scan_kernel(const int* cnt0, const int* cnt1,
                                                    int* rp0, int* rp1,
                                                    float* dinv0, float* dinv1) {
  const int* cnt = blockIdx.x ? cnt1 : cnt0;
  int* rp = blockIdx.x ? rp1 : rp0;
  float* dinv = blockIdx.x ? dinv1 : dinv0;
  __shared__ int sd[1024];
  int tid = threadIdx.x;
  int base = tid * 20;
  int pref[20];
  int run = 0;
#pragma unroll
  for (int k = 0; k < 20; k++) {
    int i = base + k;
    int c = (i < N_NODES) ? cnt[i] : 0;
    if (i < N_NODES) dinv[i] = rsqrtf((float)c + 1.0f);
    run += c;
    pref[k] = run;
  }
  sd[tid] = run;
  __syncthreads();
  for (int off = 1; off < 1024; off <<= 1) {
    int v = (tid >= off) ? sd[tid - off] : 0;
    __syncthreads();
    sd[tid] += v;
    __syncthreads();
  }
  int offset = sd[tid] - run;
  if (tid == 0) rp[0] = 0;
#pragma unroll
  for (int k = 0; k < 20; k++) {
    int i = base + k;
    if (i < N_NODES) rp[i + 1] = offset + pref[k];
  }
}

// ---------------------------------------------------------------------------
// fill (r17): 512-thread blocks (same occupancy logic as count_rank; tl =
// 20KB -> 4 blocks/CU wave-capped). First 625 blocks/branch: eg scatter
// (625*512 = 320000 exact). Last NCHUNK*4 blocks/branch: privatized t.
// grid (625 + NCHUNK*4, 2) x 512.
// ---------------------------------------------------------------------------
__global__ __launch_bounds__(512) void fill_kernel(
    const void* e0, const void* e1,
    const float* dinv0, const float* dinv1,
    const int* rp0, const int* rp1,
    const int* rank0, const int* rank1,
    unsigned int* eg0, unsigned int* eg1,
    float* t0, float* t1, const int* flags) {
  int b = blockIdx.y;
  const void* e = b ? e1 : e0;
  const float* dinv = b ? dinv1 : dinv0;
  bool w64 = flags[1] != 0;
  const int* s32 = (const int*)e;
  const int* d32 = (const int*)e + N_EDGES;
  const long long* s64 = (const long long*)e;
  const long long* d64 = (const long long*)e + N_EDGES;
  if (blockIdx.x < 625) {                 // eg-scatter role
    const int* rp = b ? rp1 : rp0;
    const int* rank = b ? rank1 : rank0;
    unsigned int* eg = b ? eg1 : eg0;
    int i = blockIdx.x * 512 + threadIdx.x;   // 625*512 = 320000 exact
    int src = w64 ? (int)s64[i] : s32[i];
    int dst = w64 ? (int)d64[i] : d32[i];
    int slot = rp[dst] + rank[i];
    eg[slot] = (unsigned int)src | ((unsigned int)f2bf(dinv[src] * dinv[dst]) << 16);
    return;
  }
  // t-accumulation role (privatized)
  float* t = b ? t1 : t0;
  int r = blockIdx.x - 625;
  int chunk = r >> 2;
  int lo = (r & 3) * NQ;
  int ebeg = chunk * (N_EDGES / NCHUNK);
  int eend = ebeg + (N_EDGES / NCHUNK);
  __shared__ float tl[NQ];
  for (int k = threadIdx.x; k < NQ; k += 512) tl[k] = 0.f;
  __syncthreads();
  for (int i = ebeg + threadIdx.x; i < eend; i += 512) {
    int src = w64 ? (int)s64[i] : s32[i];
    unsigned q = (unsigned)(src - lo);
    if (q < NQ) {
      int dst = w64 ? (int)d64[i] : d32[i];
      atomicAdd(&tl[q], dinv[dst]);
    }
  }
  __syncthreads();
  for (int k = threadIdx.x; k < NQ; k += 512) {
    float v = tl[k];
    if (v != 0.f) atomicAdd(&t[lo + k], v);   // coalesced merge, skip zeros
  }
}

// ---------------------------------------------------------------------------
// gemm (r15, verified): C[M,256] = A[M,256] @ W, B read DIRECTLY from
// precomputed Wt[n][k] bf16 (L2-broadcast). A-tile staged to LDS once,
// 1 barrier, 8 barrier-free k-steps x 8 MFMA/wave. grid (625, 1, 2).
// ---------------------------------------------------------------------------
__global__ __launch_bounds__(256) void gemm_kernel(
    const void* __restrict__ A0, const void* __restrict__ A1,
    const ushort* __restrict__ Wt,
    ushort* __restrict__ C0, ushort* __restrict__ C1,
    int maybe_f32, const int* __restrict__ flags) {
  const void* A = blockIdx.z ? A1 : A0;
  ushort* C = blockIdx.z ? C1 : C0;
  bool af32 = maybe_f32 && (flags[0] != 0);
  int m0 = blockIdx.x * 32;
  __shared__ __align__(16) ushort As[32][264];
  int tid = threadIdx.x;
  int wave = tid >> 6, lane = tid & 63;
  int quad = lane >> 4, r16 = lane & 15;
  int nb = wave * 64;             // wave's N-range
  {
    int row = tid >> 3, c0 = (tid & 7) * 32;
    int gr = m0 + row;            // always < 20000 (625*32 exact)
    if (af32) {
      const float* pA = (const float*)A + gr * 256 + c0;
      ushort* d = &As[row][c0];
#pragma unroll
      for (int s = 0; s < 8; s++) {
        float4 v = *(const float4*)(pA + s * 4);
        d[s * 4 + 0] = f2bf(v.x); d[s * 4 + 1] = f2bf(v.y);
        d[s * 4 + 2] = f2bf(v.z); d[s * 4 + 3] = f2bf(v.w);
      }
    } else {
      const ushort* pA = (const ushort*)A + gr * 256 + c0;
#pragma unroll
      for (int s = 0; s < 4; s++)
        *(int4*)&As[row][c0 + s * 8] = *(const int4*)(pA + s * 8);
    }
  }
  __syncthreads();
  f32x4 acc[2][4];
#pragma unroll
  for (int m = 0; m < 2; m++)
#pragma unroll
    for (int n = 0; n < 4; n++) acc[m][n] = (f32x4){0.f, 0.f, 0.f, 0.f};
#pragma unroll
  for (int k0 = 0; k0 < 256; k0 += 32) {
    bf16x8 a0 = *(const bf16x8*)&As[r16][k0 + quad * 8];
    bf16x8 a1 = *(const bf16x8*)&As[16 + r16][k0 + quad * 8];
    const ushort* wp = Wt + (nb + r16) * 256 + k0 + quad * 8;
    bf16x8 bb0 = *(const bf16x8*)(wp);
    bf16x8 bb1 = *(const bf16x8*)(wp + 16 * 256);
    bf16x8 bb2 = *(const bf16x8*)(wp + 32 * 256);
    bf16x8 bb3 = *(const bf16x8*)(wp + 48 * 256);
    acc[0][0] = __builtin_amdgcn_mfma_f32_16x16x32_bf16(a0, bb0, acc[0][0], 0, 0, 0);
    acc[0][1] = __builtin_amdgcn_mfma_f32_16x16x32_bf16(a0, bb1, acc[0][1], 0, 0, 0);
    acc[0][2] = __builtin_amdgcn_mfma_f32_16x16x32_bf16(a0, bb2, acc[0][2], 0, 0, 0);
    acc[0][3] = __builtin_amdgcn_mfma_f32_16x16x32_bf16(a0, bb3, acc[0][3], 0, 0, 0);
    acc[1][0] = __builtin_amdgcn_mfma_f32_16x16x32_bf16(a1, bb0, acc[1][0], 0, 0, 0);
    acc[1][1] = __builtin_amdgcn_mfma_f32_16x16x32_bf16(a1, bb1, acc[1][1], 0, 0, 0);
    acc[1][2] = __builtin_amdgcn_mfma_f32_16x16x32_bf16(a1, bb2, acc[1][2], 0, 0, 0);
    acc[1][3] = __builtin_amdgcn_mfma_f32_16x16x32_bf16(a1, bb3, acc[1][3], 0, 0, 0);
  }
#pragma unroll
  for (int m = 0; m < 2; m++) {
    int grb = m0 + m * 16 + quad * 4;
#pragma unroll
    for (int r = 0; r < 4; r++) {
      int gr = grb + r;
      ushort* cp = C + gr * 256 + nb + r16;
      cp[0]  = f2bf(acc[m][0][r]);
      cp[16] = f2bf(acc[m][1][r]);
      cp[32] = f2bf(acc[m][2][r]);
      cp[48] = f2bf(acc[m][3][r]);
    }
  }
}

// ---------------------------------------------------------------------------
// agg (r17): feature-sliced gather (structure at its replicated ~41us
// plateau -- r1/r14/r16 all equal). NEW: fuse==1 (layer 2) folds the
// pooled colsum in: pooled += c_i * relu(...) via LDS slice-reduce + 64
// global float atomicAdds per block into P[2][256] (625 writers/address
// at ~1/56ns arrival -- no queue buildup). Kills the colsum kernel, the
// H2 write (20.5MB) and its re-read; pools UN-quantized fp32 (closer to
// ref). grid (625, 2branch, 4slice).
// ---------------------------------------------------------------------------
__global__ __launch_bounds__(256) void agg_kernel(
    const ushort* __restrict__ XW0, const ushort* __restrict__ XW1,
    const float* __restrict__ dinv0, const float* __restrict__ dinv1,
    const int* __restrict__ rp0, const int* __restrict__ rp1,
    const unsigned int* __restrict__ eg0, const unsigned int* __restrict__ eg1,
    const void* __restrict__ bias,
    ushort* __restrict__ H0, ushort* __restrict__ H1,
    const float* __restrict__ t0, const float* __restrict__ t1,
    float* __restrict__ Pacc, int fuse,
    const int* __restrict__ flags) {
  __shared__ float ps[64];
  int b = blockIdx.y;                           // branch (middle dim)
  const ushort* XW = b ? XW1 : XW0;
  const float* dinv = b ? dinv1 : dinv0;
  const int* rp = b ? rp1 : rp0;
  const unsigned int* eg = b ? eg1 : eg0;
  ushort* H = b ? H1 : H0;
  if (threadIdx.x < 64) ps[threadIdx.x] = 0.f;
  __syncthreads();
  int wave = threadIdx.x >> 6, lane = threadIdx.x & 63;
  int grp = lane >> 3;                          // node within wave (0..7)
  int fo = (lane & 7) * 8 + blockIdx.z * 64;    // slice on z
  int i = blockIdx.x * 32 + wave * 8 + grp;     // 625*32 = 20000 exact
  float di = dinv[i];
  float selfw = di * di;
  us8 v = *(const us8*)(XW + i * 256 + fo);
  float acc[8], acc2[8];
#pragma unroll
  for (int k = 0; k < 8; k++) { acc[k] = selfw * bf2f(v[k]); acc2[k] = 0.f; }
  int e = rp[i], eend = rp[i + 1];
  for (; e + 4 <= eend; e += 4) {
    unsigned int p0 = eg[e], p1 = eg[e + 1], p2 = eg[e + 2], p3 = eg[e + 3];
    us8 r0 = *(const us8*)(XW + (p0 & 0xFFFFu) * 256 + fo);
    us8 r1 = *(const us8*)(XW + (p1 & 0xFFFFu) * 256 + fo);
    us8 r2 = *(const us8*)(XW + (p2 & 0xFFFFu) * 256 + fo);
    us8 r3 = *(const us8*)(XW + (p3 & 0xFFFFu) * 256 + fo);
    float w0 = bf2f((ushort)(p0 >> 16)), w1 = bf2f((ushort)(p1 >> 16));
    float w2 = bf2f((ushort)(p2 >> 16)), w3 = bf2f((ushort)(p3 >> 16));
#pragma unroll
    for (int k = 0; k < 8; k++) {
      acc[k]  += w0 * bf2f(r0[k]);
      acc2[k] += w1 * bf2f(r1[k]);
      acc[k]  += w2 * bf2f(r2[k]);
      acc2[k] += w3 * bf2f(r3[k]);
    }
  }
  for (; e < eend; e++) {
    unsigned int pp = eg[e];
    us8 r = *(const us8*)(XW + (pp & 0xFFFFu) * 256 + fo);
    float w = bf2f((ushort)(pp >> 16));
#pragma unroll
    for (int k = 0; k < 8; k++) acc[k] += w * bf2f(r[k]);
  }
  float bv[8];
  if (flags[0]) {
    const float* bf = (const float*)bias + fo;
    float4 c0 = *(const float4*)bf;
    float4 c1 = *(const float4*)(bf + 4);
    bv[0] = c0.x; bv[1] = c0.y; bv[2] = c0.z; bv[3] = c0.w;
    bv[4] = c1.x; bv[5] = c1.y; bv[6] = c1.z; bv[7] = c1.w;
  } else {
    us8 bb = *(const us8*)((const ushort*)bias + fo);
#pragma unroll
    for (int k = 0; k < 8; k++) bv[k] = bf2f(bb[k]);
  }
  if (fuse) {
    float ti = (b ? t1 : t0)[i];
    float ci = di * (ti + di);
    int fl = (lane & 7) * 8;
#pragma unroll
    for (int k = 0; k < 8; k++) {
      float hv = fmaxf(acc[k] + acc2[k] + bv[k], 0.f);
      atomicAdd(&ps[fl + k], ci * hv);
    }
  } else {
    us8 o;
#pragma unroll
    for (int k = 0; k < 8; k++)
      o[k] = f2bf(fmaxf(acc[k] + acc2[k] + bv[k], 0.f));
    *(us8*)(H + i * 256 + fo) = o;
  }
  __syncthreads();
  if (fuse && threadIdx.x < 64)
    atomicAdd(&Pacc[b * 256 + blockIdx.z * 64 + threadIdx.x], ps[threadIdx.x]);
}

// pooled = ((P0+P1)@W3)/(2N)+b3 ; out = pooled@Wl + bl.
__global__ __launch_bounds__(256) void final_kernel(
    const float* __restrict__ P,
    const void* __restrict__ W3, const void* __restrict__ b3,
    const void* __restrict__ Wl, const void* __restrict__ bl,
    void* __restrict__ out, const int* __restrict__ flags) {
  __shared__ float v[256];
  __shared__ float pooled[256];
  bool f32 = flags[0] != 0;
  int t = threadIdx.x;
  v[t] = P[t] + P[256 + t];
  __syncthreads();
  float acc = 0.f;
  if (f32) {
    const float* W3f = (const float*)W3;
    for (int f = 0; f < 256; f++) acc += v[f] * W3f[f * 256 + t];
    pooled[t] = acc * (1.0f / (2.0f * N_NODES)) + ((const float*)b3)[t];
  } else {
    const ushort* W3b = (const ushort*)W3;
    for (int f = 0; f < 256; f++) acc += v[f] * bf2f(W3b[f * 256 + t]);
    pooled[t] = acc * (1.0f / (2.0f * N_NODES)) + bf2f(((const ushort*)b3)[t]);
  }
  __syncthreads();
  if (t < 5) {
    float o;
    if (f32) {
      o = ((const float*)bl)[t];
      for (int h = 0; h < 256; h++) o += pooled[h] * ((const float*)Wl)[h * 5 + t];
      ((float*)out)[t] = o;
    } else {
      o = bf2f(((const ushort*)bl)[t]);
      for (int h = 0; h < 256; h++) o += pooled[h] * bf2f(((const ushort*)Wl)[h * 5 + t]);
      ((ushort*)out)[t] = f2bf(o);
    }
  }
}

extern "C" void kernel_launch(void* const* d_in, const int* in_sizes, int n_in,
                              void* d_out, int out_size, void* d_ws, size_t ws_size,
                              hipStream_t stream) {
  const void* x1 = d_in[0];
  const void* ei1 = d_in[1];
  const void* x2 = d_in[2];
  const void* ei2 = d_in[3];
  const void* W1 = d_in[4];
  const void* b1 = d_in[5];
  const void* W2 = d_in[6];
  const void* b2 = d_in[7];
  const void* W3 = d_in[8];
  const void* b3 = d_in[9];
  const void* Wl = d_in[10];
  const void* bl = d_in[11];

  char* p = (char*)d_ws;
  auto alloc = [&](size_t bytes) {
    char* r = p;
    p += (bytes + 255) & ~size_t(255);
    return r;
  };
  int* flags   = (int*)alloc(256);
  float* dinv0 = (float*)alloc(N_NODES * 4);
  float* dinv1 = (float*)alloc(N_NODES * 4);
  float* t0    = (float*)alloc(N_NODES * 4);
  float* t1    = (float*)alloc(N_NODES * 4);
  int* cnt0    = (int*)alloc(N_NODES * 4);
  int* cnt1    = (int*)alloc(N_NODES * 4);
  int* rp0     = (int*)alloc((N_NODES + 1) * 4);
  int* rp1     = (int*)alloc((N_NODES + 1) * 4);
  unsigned int* eg0 = (unsigned int*)alloc((size_t)N_EDGES * 4);
  unsigned int* eg1 = (unsigned int*)alloc((size_t)N_EDGES * 4);
  float* Pp    = (float*)alloc(512 * 4);
  ushort* wt1  = (ushort*)alloc(256 * 256 * 2);
  ushort* wt2  = (ushort*)alloc(256 * 256 * 2);
  ushort* xw0  = (ushort*)alloc((size_t)N_NODES * HID * 2);
  ushort* xw1  = (ushort*)alloc((size_t)N_NODES * HID * 2);
  ushort* h0   = (ushort*)alloc((size_t)N_NODES * HID * 2);
  ushort* h1   = (ushort*)alloc((size_t)N_NODES * HID * 2);
  // rank aliases xw0 (rank dead after fill; xw0 first written by gemm1).
  int* rank0  = (int*)xw0;
  int* rank1  = rank0 + N_EDGES;

  // --- init+detect, wt, privatized count+rank, scan, fill ---
  init_detect_kernel<<<(N_NODES + 255) / 256 + 1, 256, 0, stream>>>(
      cnt0, cnt1, t0, t1, Pp, x1, ei1, flags);
  wt_kernel<<<512, 256, 0, stream>>>(W1, W2, wt1, wt2, flags);
  count_rank_kernel<<<dim3(NCHUNK * 4, 2), 512, 0, stream>>>(
      ei1, ei2, cnt0, cnt1, rank0, rank1, flags);
  scan_kernel<<<2, 1024, 0, stream>>>(cnt0, cnt1, rp0, rp1, dinv0, dinv1);
  fill_kernel<<<dim3(625 + NCHUNK * 4, 2), 512, 0, stream>>>(
      ei1, ei2, dinv0, dinv1, rp0, rp1, rank0, rank1, eg0, eg1, t0, t1, flags);

  // Layer 1: xw = x @ W1 ; h = relu(agg(xw) + b1)
  gemm_kernel<<<dim3(625, 1, 2), 256, 0, stream>>>(x1, x2, wt1, xw0, xw1, 1, flags);
  agg_kernel<<<dim3(625, 2, 4), 256, 0, stream>>>(
      xw0, xw1, dinv0, dinv1, rp0, rp1, eg0, eg1, b1, h0, h1,
      t0, t1, Pp, 0, flags);

  // Layer 2: xw = h @ W2 ; agg2 fuses relu+pooled colsum into P (no H2)
  gemm_kernel<<<dim3(625, 1, 2), 256, 0, stream>>>(h0, h1, wt2, xw0, xw1, 0, flags);
  agg_kernel<<<dim3(625, 2, 4), 256, 0, stream>>>(
      xw0, xw1, dinv0, dinv1, rp0, rp1, eg0, eg1, b2, h0, h1,
      t0, t1, Pp, 1, flags);

  // out = ((P0+P1)@W3/(2N)+b3)@Wl + bl
  final_kernel<<<1, 256, 0, stream>>>(Pp, W3, b3, Wl, bl, d_out, flags);
}

// Round 9
// 374.863 us; speedup vs baseline: 1.0736x; 1.0736x over previous
//
#include <hip/hip_runtime.h>
#include <hip/hip_bf16.h>

#define N_NODES 20000
#define N_EDGES 320000
#define HID 256
#define NQ 5000          // nodes per quarter (histogram privatization)
#define NCHUNK 64        // edge chunks per branch (r12: occupancy fix, verified)

typedef __attribute__((ext_vector_type(8))) short bf16x8;   // 8 bf16 = 4 VGPRs (MFMA A/B frag)
typedef __attribute__((ext_vector_type(4))) float f32x4;    // MFMA C/D frag
typedef __attribute__((ext_vector_type(8))) unsigned short us8;  // 16B row chunk

__device__ __forceinline__ float bf2f(ushort u) {
  union { unsigned int i; float f; } v; v.i = ((unsigned int)u) << 16; return v.f;
}
__device__ __forceinline__ ushort f2bf(float f) {
  union { float f; unsigned int i; } v; v.f = f;
  unsigned int r = v.i + 0x7FFFu + ((v.i >> 16) & 1u);   // RNE
  return (ushort)(r >> 16);
}

// ---------------------------------------------------------------------------
// init (zero cnt/t/P) + runtime dtype detection fused.
// flags[0]=1 -> x/weights fp32 (else bf16). flags[1]=1 -> edges int64.
// P = 64 buckets x 512 floats (r9: bucketed pooled accumulator).
// ---------------------------------------------------------------------------
__global__ void init_detect_kernel(int* cnt0, int* cnt1, float* t0, float* t1,
                                   float* P,
                                   const void* x1, const void* ei1, int* flags) {
  if (blockIdx.x == gridDim.x - 1) {
    __shared__ int cnt_wild, cnt_oddnz;
    if (threadIdx.x == 0) { cnt_wild = 0; cnt_oddnz = 0; }
    __syncthreads();
    const ushort* xu = (const ushort*)x1;
    int wild = 0;
#pragma unroll
    for (int k = 0; k < 4; k++) {
      ushort u = xu[threadIdx.x * 4 + k];
      int ex = (u >> 7) & 0xFF;
      if (ex >= 0x90) wild++;
    }
    if (wild) atomicAdd(&cnt_wild, wild);
    const int* ii = (const int*)ei1;
    if (ii[threadIdx.x * 2 + 1] != 0) atomicAdd(&cnt_oddnz, 1);
    __syncthreads();
    if (threadIdx.x == 0) {
      flags[0] = (cnt_wild > 64) ? 1 : 0;
      flags[1] = (cnt_oddnz < 8) ? 1 : 0;
    }
    return;
  }
  int i = blockIdx.x * blockDim.x + threadIdx.x;
  if (i < N_NODES) { cnt0[i] = 0; cnt1[i] = 0; t0[i] = 0.f; t1[i] = 0.f; }
  if (i < 16384) { P[i] = 0.f; P[i + 16384] = 0.f; }   // 64*512 = 32768
}

// ---------------------------------------------------------------------------
// wt (r15): W[k][n] -> Wt[n][k] bf16, ONCE. Blocks 0..255 = W1 row k,
// 256..511 = W2 row k. Kills the per-gemm-block redundant transpose.
// ---------------------------------------------------------------------------
__global__ __launch_bounds__(256) void wt_kernel(
    const void* __restrict__ W1, const void* __restrict__ W2,
    ushort* __restrict__ Wt1, ushort* __restrict__ Wt2,
    const int* __restrict__ flags) {
  bool f32 = flags[0] != 0;
  int which = blockIdx.x >> 8;
  int k = blockIdx.x & 255;
  const void* W = which ? W2 : W1;
  ushort* Wt = which ? Wt2 : Wt1;
  int n = threadIdx.x;
  ushort v = f32 ? f2bf(((const float*)W)[k * 256 + n])
                 : ((const ushort*)W)[k * 256 + n];
  Wt[n * 256 + k] = v;
}

// ---------------------------------------------------------------------------
// count_rank (r17, kept): 512-thread blocks -> 4 blocks/CU (verified ~21us
// net prep win in r8). grid (NCHUNK*4, 2) x 512.
// ---------------------------------------------------------------------------
__global__ __launch_bounds__(512) void count_rank_kernel(
    const void* e0, const void* e1, int* cnt0, int* cnt1,
    int* rank0, int* rank1, const int* flags) {
  int b = blockIdx.y;
  const void* e = b ? e1 : e0;
  int* cnt = b ? cnt1 : cnt0;
  int* rank = b ? rank1 : rank0;
  int chunk = blockIdx.x >> 2;
  int lo = (blockIdx.x & 3) * NQ;
  int ebeg = chunk * (N_EDGES / NCHUNK);
  int eend = ebeg + (N_EDGES / NCHUNK);
  __shared__ int hist[NQ];
  __shared__ int base[NQ];
  for (int k = threadIdx.x; k < NQ; k += 512) hist[k] = 0;
  __syncthreads();
  bool w64 = flags[1] != 0;
  const int* d32 = (const int*)e + N_EDGES;
  const long long* d64 = (const long long*)e + N_EDGES;
  for (int i = ebeg + threadIdx.x; i < eend; i += 512) {
    int d = w64 ? (int)d64[i] : d32[i];
    unsigned q = (unsigned)(d - lo);
    if (q < NQ) atomicAdd(&hist[q], 1);
  }
  __syncthreads();
  for (int k = threadIdx.x; k < NQ; k += 512) {
    int h = hist[k];
    if (h) base[k] = atomicAdd(&cnt[lo + k], h);  // coalesced merge, skip zeros
    hist[k] = 0;                                  // reuse as local rank ctr
  }
  __syncthreads();
  for (int i = ebeg + threadIdx.x; i < eend; i += 512) {
    int d = w64 ? (int)d64[i] : d32[i];
    unsigned q = (unsigned)(d - lo);
    if (q < NQ) rank[i] = base[q] + atomicAdd(&hist[q], 1);
  }
}

// Exclusive scan -> CSR row_ptr, fused with dinv = rsqrt(cnt+1).
__global__ __launch_bounds__(1024) void scan_kernel(const int* cnt0, const int* cnt1,
                                                    int* rp0, int* rp1,
                                                    float* dinv0, float* dinv1) {
  const int* cnt = blockIdx.x ? cnt1 : cnt0;
  int* rp = blockIdx.x ? rp1 : rp0;
  float* dinv = blockIdx.x ? dinv1 : dinv0;
  __shared__ int sd[1024];
  int tid = threadIdx.x;
  int base = tid * 20;
  int pref[20];
  int run = 0;
#pragma unroll
  for (int k = 0; k < 20; k++) {
    int i = base + k;
    int c = (i < N_NODES) ? cnt[i] : 0;
    if (i < N_NODES) dinv[i] = rsqrtf((float)c + 1.0f);
    run += c;
    pref[k] = run;
  }
  sd[tid] = run;
  __syncthreads();
  for (int off = 1; off < 1024; off <<= 1) {
    int v = (tid >= off) ? sd[tid - off] : 0;
    __syncthreads();
    sd[tid] += v;
    __syncthreads();
  }
  int offset = sd[tid] - run;
  if (tid == 0) rp[0] = 0;
#pragma unroll
  for (int k = 0; k < 20; k++) {
    int i = base + k;
    if (i < N_NODES) rp[i + 1] = offset + pref[k];
  }
}

// ---------------------------------------------------------------------------
// fill (r17, kept): 512-thread blocks. First 625 blocks/branch: eg scatter
// (625*512 = 320000 exact). Last NCHUNK*4 blocks/branch: privatized t.
// grid (625 + NCHUNK*4, 2) x 512.
// ---------------------------------------------------------------------------
__global__ __launch_bounds__(512) void fill_kernel(
    const void* e0, const void* e1,
    const float* dinv0, const float* dinv1,
    const int* rp0, const int* rp1,
    const int* rank0, const int* rank1,
    unsigned int* eg0, unsigned int* eg1,
    float* t0, float* t1, const int* flags) {
  int b = blockIdx.y;
  const void* e = b ? e1 : e0;
  const float* dinv = b ? dinv1 : dinv0;
  bool w64 = flags[1] != 0;
  const int* s32 = (const int*)e;
  const int* d32 = (const int*)e + N_EDGES;
  const long long* s64 = (const long long*)e;
  const long long* d64 = (const long long*)e + N_EDGES;
  if (blockIdx.x < 625) {                 // eg-scatter role
    const int* rp = b ? rp1 : rp0;
    const int* rank = b ? rank1 : rank0;
    unsigned int* eg = b ? eg1 : eg0;
    int i = blockIdx.x * 512 + threadIdx.x;   // 625*512 = 320000 exact
    int src = w64 ? (int)s64[i] : s32[i];
    int dst = w64 ? (int)d64[i] : d32[i];
    int slot = rp[dst] + rank[i];
    eg[slot] = (unsigned int)src | ((unsigned int)f2bf(dinv[src] * dinv[dst]) << 16);
    return;
  }
  // t-accumulation role (privatized)
  float* t = b ? t1 : t0;
  int r = blockIdx.x - 625;
  int chunk = r >> 2;
  int lo = (r & 3) * NQ;
  int ebeg = chunk * (N_EDGES / NCHUNK);
  int eend = ebeg + (N_EDGES / NCHUNK);
  __shared__ float tl[NQ];
  for (int k = threadIdx.x; k < NQ; k += 512) tl[k] = 0.f;
  __syncthreads();
  for (int i = ebeg + threadIdx.x; i < eend; i += 512) {
    int src = w64 ? (int)s64[i] : s32[i];
    unsigned q = (unsigned)(src - lo);
    if (q < NQ) {
      int dst = w64 ? (int)d64[i] : d32[i];
      atomicAdd(&tl[q], dinv[dst]);
    }
  }
  __syncthreads();
  for (int k = threadIdx.x; k < NQ; k += 512) {
    float v = tl[k];
    if (v != 0.f) atomicAdd(&t[lo + k], v);   // coalesced merge, skip zeros
  }
}

// ---------------------------------------------------------------------------
// gemm (r15, verified): C[M,256] = A[M,256] @ W, B read DIRECTLY from
// precomputed Wt[n][k] bf16 (L2-broadcast). A-tile staged to LDS once,
// 1 barrier, 8 barrier-free k-steps x 8 MFMA/wave. grid (625, 1, 2).
// ---------------------------------------------------------------------------
__global__ __launch_bounds__(256) void gemm_kernel(
    const void* __restrict__ A0, const void* __restrict__ A1,
    const ushort* __restrict__ Wt,
    ushort* __restrict__ C0, ushort* __restrict__ C1,
    int maybe_f32, const int* __restrict__ flags) {
  const void* A = blockIdx.z ? A1 : A0;
  ushort* C = blockIdx.z ? C1 : C0;
  bool af32 = maybe_f32 && (flags[0] != 0);
  int m0 = blockIdx.x * 32;
  __shared__ __align__(16) ushort As[32][264];
  int tid = threadIdx.x;
  int wave = tid >> 6, lane = tid & 63;
  int quad = lane >> 4, r16 = lane & 15;
  int nb = wave * 64;             // wave's N-range
  {
    int row = tid >> 3, c0 = (tid & 7) * 32;
    int gr = m0 + row;            // always < 20000 (625*32 exact)
    if (af32) {
      const float* pA = (const float*)A + gr * 256 + c0;
      ushort* d = &As[row][c0];
#pragma unroll
      for (int s = 0; s < 8; s++) {
        float4 v = *(const float4*)(pA + s * 4);
        d[s * 4 + 0] = f2bf(v.x); d[s * 4 + 1] = f2bf(v.y);
        d[s * 4 + 2] = f2bf(v.z); d[s * 4 + 3] = f2bf(v.w);
      }
    } else {
      const ushort* pA = (const ushort*)A + gr * 256 + c0;
#pragma unroll
      for (int s = 0; s < 4; s++)
        *(int4*)&As[row][c0 + s * 8] = *(const int4*)(pA + s * 8);
    }
  }
  __syncthreads();
  f32x4 acc[2][4];
#pragma unroll
  for (int m = 0; m < 2; m++)
#pragma unroll
    for (int n = 0; n < 4; n++) acc[m][n] = (f32x4){0.f, 0.f, 0.f, 0.f};
#pragma unroll
  for (int k0 = 0; k0 < 256; k0 += 32) {
    bf16x8 a0 = *(const bf16x8*)&As[r16][k0 + quad * 8];
    bf16x8 a1 = *(const bf16x8*)&As[16 + r16][k0 + quad * 8];
    const ushort* wp = Wt + (nb + r16) * 256 + k0 + quad * 8;
    bf16x8 bb0 = *(const bf16x8*)(wp);
    bf16x8 bb1 = *(const bf16x8*)(wp + 16 * 256);
    bf16x8 bb2 = *(const bf16x8*)(wp + 32 * 256);
    bf16x8 bb3 = *(const bf16x8*)(wp + 48 * 256);
    acc[0][0] = __builtin_amdgcn_mfma_f32_16x16x32_bf16(a0, bb0, acc[0][0], 0, 0, 0);
    acc[0][1] = __builtin_amdgcn_mfma_f32_16x16x32_bf16(a0, bb1, acc[0][1], 0, 0, 0);
    acc[0][2] = __builtin_amdgcn_mfma_f32_16x16x32_bf16(a0, bb2, acc[0][2], 0, 0, 0);
    acc[0][3] = __builtin_amdgcn_mfma_f32_16x16x32_bf16(a0, bb3, acc[0][3], 0, 0, 0);
    acc[1][0] = __builtin_amdgcn_mfma_f32_16x16x32_bf16(a1, bb0, acc[1][0], 0, 0, 0);
    acc[1][1] = __builtin_amdgcn_mfma_f32_16x16x32_bf16(a1, bb1, acc[1][1], 0, 0, 0);
    acc[1][2] = __builtin_amdgcn_mfma_f32_16x16x32_bf16(a1, bb2, acc[1][2], 0, 0, 0);
    acc[1][3] = __builtin_amdgcn_mfma_f32_16x16x32_bf16(a1, bb3, acc[1][3], 0, 0, 0);
  }
#pragma unroll
  for (int m = 0; m < 2; m++) {
    int grb = m0 + m * 16 + quad * 4;
#pragma unroll
    for (int r = 0; r < 4; r++) {
      int gr = grb + r;
      ushort* cp = C + gr * 256 + nb + r16;
      cp[0]  = f2bf(acc[m][0][r]);
      cp[16] = f2bf(acc[m][1][r]);
      cp[32] = f2bf(acc[m][2][r]);
      cp[48] = f2bf(acc[m][3][r]);
    }
  }
}

// ---------------------------------------------------------------------------
// agg (r18): feature-sliced gather (plateau structure). fuse==1 folds the
// pooled colsum in. r8 post-mortem: global atomics into a SINGLE 512-float
// array from 5000 blocks = 625 device-scope RMWs/address on ~32 cache lines
// ping-ponging across 8 non-coherent XCD L2s -> 110us (2.7x regression).
// r9 fix: 64 BUCKETS (Pacc[64][512], bucket = blockIdx.x & 63) -> ~10
// writers/address spread over 128KB; end barrier now fuse-only so layer-1
// agg keeps independent wave retirement. grid (625, 2branch, 4slice).
// ---------------------------------------------------------------------------
__global__ __launch_bounds__(256) void agg_kernel(
    const ushort* __restrict__ XW0, const ushort* __restrict__ XW1,
    const float* __restrict__ dinv0, const float* __restrict__ dinv1,
    const int* __restrict__ rp0, const int* __restrict__ rp1,
    const unsigned int* __restrict__ eg0, const unsigned int* __restrict__ eg1,
    const void* __restrict__ bias,
    ushort* __restrict__ H0, ushort* __restrict__ H1,
    const float* __restrict__ t0, const float* __restrict__ t1,
    float* __restrict__ Pacc, int fuse,
    const int* __restrict__ flags) {
  __shared__ float ps[64];
  int b = blockIdx.y;                           // branch (middle dim)
  const ushort* XW = b ? XW1 : XW0;
  const float* dinv = b ? dinv1 : dinv0;
  const int* rp = b ? rp1 : rp0;
  const unsigned int* eg = b ? eg1 : eg0;
  ushort* H = b ? H1 : H0;
  if (fuse) {
    if (threadIdx.x < 64) ps[threadIdx.x] = 0.f;
    __syncthreads();
  }
  int wave = threadIdx.x >> 6, lane = threadIdx.x & 63;
  int grp = lane >> 3;                          // node within wave (0..7)
  int fo = (lane & 7) * 8 + blockIdx.z * 64;    // slice on z
  int i = blockIdx.x * 32 + wave * 8 + grp;     // 625*32 = 20000 exact
  float di = dinv[i];
  float selfw = di * di;
  us8 v = *(const us8*)(XW + i * 256 + fo);
  float acc[8], acc2[8];
#pragma unroll
  for (int k = 0; k < 8; k++) { acc[k] = selfw * bf2f(v[k]); acc2[k] = 0.f; }
  int e = rp[i], eend = rp[i + 1];
  for (; e + 4 <= eend; e += 4) {
    unsigned int p0 = eg[e], p1 = eg[e + 1], p2 = eg[e + 2], p3 = eg[e + 3];
    us8 r0 = *(const us8*)(XW + (p0 & 0xFFFFu) * 256 + fo);
    us8 r1 = *(const us8*)(XW + (p1 & 0xFFFFu) * 256 + fo);
    us8 r2 = *(const us8*)(XW + (p2 & 0xFFFFu) * 256 + fo);
    us8 r3 = *(const us8*)(XW + (p3 & 0xFFFFu) * 256 + fo);
    float w0 = bf2f((ushort)(p0 >> 16)), w1 = bf2f((ushort)(p1 >> 16));
    float w2 = bf2f((ushort)(p2 >> 16)), w3 = bf2f((ushort)(p3 >> 16));
#pragma unroll
    for (int k = 0; k < 8; k++) {
      acc[k]  += w0 * bf2f(r0[k]);
      acc2[k] += w1 * bf2f(r1[k]);
      acc[k]  += w2 * bf2f(r2[k]);
      acc2[k] += w3 * bf2f(r3[k]);
    }
  }
  for (; e < eend; e++) {
    unsigned int pp = eg[e];
    us8 r = *(const us8*)(XW + (pp & 0xFFFFu) * 256 + fo);
    float w = bf2f((ushort)(pp >> 16));
#pragma unroll
    for (int k = 0; k < 8; k++) acc[k] += w * bf2f(r[k]);
  }
  float bv[8];
  if (flags[0]) {
    const float* bf = (const float*)bias + fo;
    float4 c0 = *(const float4*)bf;
    float4 c1 = *(const float4*)(bf + 4);
    bv[0] = c0.x; bv[1] = c0.y; bv[2] = c0.z; bv[3] = c0.w;
    bv[4] = c1.x; bv[5] = c1.y; bv[6] = c1.z; bv[7] = c1.w;
  } else {
    us8 bb = *(const us8*)((const ushort*)bias + fo);
#pragma unroll
    for (int k = 0; k < 8; k++) bv[k] = bf2f(bb[k]);
  }
  if (fuse) {
    float ti = (b ? t1 : t0)[i];
    float ci = di * (ti + di);
    int fl = (lane & 7) * 8;
#pragma unroll
    for (int k = 0; k < 8; k++) {
      float hv = fmaxf(acc[k] + acc2[k] + bv[k], 0.f);
      atomicAdd(&ps[fl + k], ci * hv);
    }
    __syncthreads();
    if (threadIdx.x < 64)
      atomicAdd(&Pacc[(blockIdx.x & 63) * 512 + b * 256 + blockIdx.z * 64 + threadIdx.x],
                ps[threadIdx.x]);
  } else {
    us8 o;
#pragma unroll
    for (int k = 0; k < 8; k++)
      o[k] = f2bf(fmaxf(acc[k] + acc2[k] + bv[k], 0.f));
    *(us8*)(H + i * 256 + fo) = o;
  }
}

// pooled = ((P0+P1)@W3)/(2N)+b3 ; out = pooled@Wl + bl. P = 64 buckets x 512.
__global__ __launch_bounds__(256) void final_kernel(
    const float* __restrict__ P,
    const void* __restrict__ W3, const void* __restrict__ b3,
    const void* __restrict__ Wl, const void* __restrict__ bl,
    void* __restrict__ out, const int* __restrict__ flags) {
  __shared__ float v[256];
  __shared__ float pooled[256];
  bool f32 = flags[0] != 0;
  int t = threadIdx.x;
  float acc0 = 0.f, acc1 = 0.f;
  for (int bk = 0; bk < 64; bk++) {
    acc0 += P[bk * 512 + t];
    acc1 += P[bk * 512 + 256 + t];
  }
  v[t] = acc0 + acc1;
  __syncthreads();
  float acc = 0.f;
  if (f32) {
    const float* W3f = (const float*)W3;
    for (int f = 0; f < 256; f++) acc += v[f] * W3f[f * 256 + t];
    pooled[t] = acc * (1.0f / (2.0f * N_NODES)) + ((const float*)b3)[t];
  } else {
    const ushort* W3b = (const ushort*)W3;
    for (int f = 0; f < 256; f++) acc += v[f] * bf2f(W3b[f * 256 + t]);
    pooled[t] = acc * (1.0f / (2.0f * N_NODES)) + bf2f(((const ushort*)b3)[t]);
  }
  __syncthreads();
  if (t < 5) {
    float o;
    if (f32) {
      o = ((const float*)bl)[t];
      for (int h = 0; h < 256; h++) o += pooled[h] * ((const float*)Wl)[h * 5 + t];
      ((float*)out)[t] = o;
    } else {
      o = bf2f(((const ushort*)bl)[t]);
      for (int h = 0; h < 256; h++) o += pooled[h] * bf2f(((const ushort*)Wl)[h * 5 + t]);
      ((ushort*)out)[t] = f2bf(o);
    }
  }
}

extern "C" void kernel_launch(void* const* d_in, const int* in_sizes, int n_in,
                              void* d_out, int out_size, void* d_ws, size_t ws_size,
                              hipStream_t stream) {
  const void* x1 = d_in[0];
  const void* ei1 = d_in[1];
  const void* x2 = d_in[2];
  const void* ei2 = d_in[3];
  const void* W1 = d_in[4];
  const void* b1 = d_in[5];
  const void* W2 = d_in[6];
  const void* b2 = d_in[7];
  const void* W3 = d_in[8];
  const void* b3 = d_in[9];
  const void* Wl = d_in[10];
  const void* bl = d_in[11];

  char* p = (char*)d_ws;
  auto alloc = [&](size_t bytes) {
    char* r = p;
    p += (bytes + 255) & ~size_t(255);
    return r;
  };
  int* flags   = (int*)alloc(256);
  float* dinv0 = (float*)alloc(N_NODES * 4);
  float* dinv1 = (float*)alloc(N_NODES * 4);
  float* t0    = (float*)alloc(N_NODES * 4);
  float* t1    = (float*)alloc(N_NODES * 4);
  int* cnt0    = (int*)alloc(N_NODES * 4);
  int* cnt1    = (int*)alloc(N_NODES * 4);
  int* rp0     = (int*)alloc((N_NODES + 1) * 4);
  int* rp1     = (int*)alloc((N_NODES + 1) * 4);
  unsigned int* eg0 = (unsigned int*)alloc((size_t)N_EDGES * 4);
  unsigned int* eg1 = (unsigned int*)alloc((size_t)N_EDGES * 4);
  float* Pp    = (float*)alloc(64 * 512 * 4);
  ushort* wt1  = (ushort*)alloc(256 * 256 * 2);
  ushort* wt2  = (ushort*)alloc(256 * 256 * 2);
  ushort* xw0  = (ushort*)alloc((size_t)N_NODES * HID * 2);
  ushort* xw1  = (ushort*)alloc((size_t)N_NODES * HID * 2);
  ushort* h0   = (ushort*)alloc((size_t)N_NODES * HID * 2);
  ushort* h1   = (ushort*)alloc((size_t)N_NODES * HID * 2);
  // rank aliases xw0 (rank dead after fill; xw0 first written by gemm1).
  int* rank0  = (int*)xw0;
  int* rank1  = rank0 + N_EDGES;

  // --- init+detect, wt, privatized count+rank, scan, fill ---
  init_detect_kernel<<<(N_NODES + 255) / 256 + 1, 256, 0, stream>>>(
      cnt0, cnt1, t0, t1, Pp, x1, ei1, flags);
  wt_kernel<<<512, 256, 0, stream>>>(W1, W2, wt1, wt2, flags);
  count_rank_kernel<<<dim3(NCHUNK * 4, 2), 512, 0, stream>>>(
      ei1, ei2, cnt0, cnt1, rank0, rank1, flags);
  scan_kernel<<<2, 1024, 0, stream>>>(cnt0, cnt1, rp0, rp1, dinv0, dinv1);
  fill_kernel<<<dim3(625 + NCHUNK * 4, 2), 512, 0, stream>>>(
      ei1, ei2, dinv0, dinv1, rp0, rp1, rank0, rank1, eg0, eg1, t0, t1, flags);

  // Layer 1: xw = x @ W1 ; h = relu(agg(xw) + b1)
  gemm_kernel<<<dim3(625, 1, 2), 256, 0, stream>>>(x1, x2, wt1, xw0, xw1, 1, flags);
  agg_kernel<<<dim3(625, 2, 4), 256, 0, stream>>>(
      xw0, xw1, dinv0, dinv1, rp0, rp1, eg0, eg1, b1, h0, h1,
      t0, t1, Pp, 0, flags);

  // Layer 2: xw = h @ W2 ; agg2 fuses relu+pooled colsum into P (no H2)
  gemm_kernel<<<dim3(625, 1, 2), 256, 0, stream>>>(h0, h1, wt2, xw0, xw1, 0, flags);
  agg_kernel<<<dim3(625, 2, 4), 256, 0, stream>>>(
      xw0, xw1, dinv0, dinv1, rp0, rp1, eg0, eg1, b2, h0, h1,
      t0, t1, Pp, 1, flags);

  // out = ((P0+P1)@W3/(2N)+b3)@Wl + bl
  final_kernel<<<1, 256, 0, stream>>>(Pp, W3, b3, Wl, bl, d_out, flags);
}

// Round 14
// 360.830 us; speedup vs baseline: 1.1153x; 1.0389x over previous
//
#include <hip/hip_runtime.h>
#include <hip/hip_bf16.h>

#define N_NODES 20000
#define N_EDGES 320000
#define HID 256
#define NQ 5000          // nodes per quarter (histogram privatization)
#define NCHUNK 64        // edge chunks per branch (r12: occupancy fix, verified)

typedef __attribute__((ext_vector_type(8))) short bf16x8;   // 8 bf16 = 4 VGPRs (MFMA A/B frag)
typedef __attribute__((ext_vector_type(4))) float f32x4;    // MFMA C/D frag
typedef __attribute__((ext_vector_type(8))) unsigned short us8;  // 16B row chunk

__device__ __forceinline__ float bf2f(ushort u) {
  union { unsigned int i; float f; } v; v.i = ((unsigned int)u) << 16; return v.f;
}
__device__ __forceinline__ ushort f2bf(float f) {
  union { float f; unsigned int i; } v; v.f = f;
  unsigned int r = v.i + 0x7FFFu + ((v.i >> 16) & 1u);   // RNE
  return (ushort)(r >> 16);
}

// ---------------------------------------------------------------------------
// init (zero cnt/t) + runtime dtype detection fused.
// flags[0]=1 -> x/weights fp32 (else bf16). flags[1]=1 -> edges int64.
// ---------------------------------------------------------------------------
__global__ void init_detect_kernel(int* cnt0, int* cnt1, float* t0, float* t1,
                                   const void* x1, const void* ei1, int* flags) {
  if (blockIdx.x == gridDim.x - 1) {
    __shared__ int cnt_wild, cnt_oddnz;
    if (threadIdx.x == 0) { cnt_wild = 0; cnt_oddnz = 0; }
    __syncthreads();
    const ushort* xu = (const ushort*)x1;
    int wild = 0;
#pragma unroll
    for (int k = 0; k < 4; k++) {
      ushort u = xu[threadIdx.x * 4 + k];
      int ex = (u >> 7) & 0xFF;
      if (ex >= 0x90) wild++;
    }
    if (wild) atomicAdd(&cnt_wild, wild);
    const int* ii = (const int*)ei1;
    if (ii[threadIdx.x * 2 + 1] != 0) atomicAdd(&cnt_oddnz, 1);
    __syncthreads();
    if (threadIdx.x == 0) {
      flags[0] = (cnt_wild > 64) ? 1 : 0;
      flags[1] = (cnt_oddnz < 8) ? 1 : 0;
    }
    return;
  }
  int i = blockIdx.x * blockDim.x + threadIdx.x;
  if (i < N_NODES) { cnt0[i] = 0; cnt1[i] = 0; t0[i] = 0.f; t1[i] = 0.f; }
}

// ---------------------------------------------------------------------------
// wt (r15, kept): W[k][n] -> Wt[n][k] bf16, ONCE.
// ---------------------------------------------------------------------------
__global__ __launch_bounds__(256) void wt_kernel(
    const void* __restrict__ W1, const void* __restrict__ W2,
    ushort* __restrict__ Wt1, ushort* __restrict__ Wt2,
    const int* __restrict__ flags) {
  bool f32 = flags[0] != 0;
  int which = blockIdx.x >> 8;
  int k = blockIdx.x & 255;
  const void* W = which ? W2 : W1;
  ushort* Wt = which ? Wt2 : Wt1;
  int n = threadIdx.x;
  ushort v = f32 ? f2bf(((const float*)W)[k * 256 + n])
                 : ((const ushort*)W)[k * 256 + n];
  Wt[n * 256 + k] = v;
}

// ---------------------------------------------------------------------------
// count_rank (r17, kept): 512-thread blocks -> 4 blocks/CU (verified -21us
// net prep win across r8/r9). grid (NCHUNK*4, 2) x 512.
// ---------------------------------------------------------------------------
__global__ __launch_bounds__(512) void count_rank_kernel(
    const void* e0, const void* e1, int* cnt0, int* cnt1,
    int* rank0, int* rank1, const int* flags) {
  int b = blockIdx.y;
  const void* e = b ? e1 : e0;
  int* cnt = b ? cnt1 : cnt0;
  int* rank = b ? rank1 : rank0;
  int chunk = blockIdx.x >> 2;
  int lo = (blockIdx.x & 3) * NQ;
  int ebeg = chunk * (N_EDGES / NCHUNK);
  int eend = ebeg + (N_EDGES / NCHUNK);
  __shared__ int hist[NQ];
  __shared__ int base[NQ];
  for (int k = threadIdx.x; k < NQ; k += 512) hist[k] = 0;
  __syncthreads();
  bool w64 = flags[1] != 0;
  const int* d32 = (const int*)e + N_EDGES;
  const long long* d64 = (const long long*)e + N_EDGES;
  for (int i = ebeg + threadIdx.x; i < eend; i += 512) {
    int d = w64 ? (int)d64[i] : d32[i];
    unsigned q = (unsigned)(d - lo);
    if (q < NQ) atomicAdd(&hist[q], 1);
  }
  __syncthreads();
  for (int k = threadIdx.x; k < NQ; k += 512) {
    int h = hist[k];
    if (h) base[k] = atomicAdd(&cnt[lo + k], h);  // coalesced merge, skip zeros
    hist[k] = 0;                                  // reuse as local rank ctr
  }
  __syncthreads();
  for (int i = ebeg + threadIdx.x; i < eend; i += 512) {
    int d = w64 ? (int)d64[i] : d32[i];
    unsigned q = (unsigned)(d - lo);
    if (q < NQ) rank[i] = base[q] + atomicAdd(&hist[q], 1);
  }
}

// Exclusive scan -> CSR row_ptr, fused with dinv = rsqrt(cnt+1).
__global__ __launch_bounds__(1024) void scan_kernel(const int* cnt0, const int* cnt1,
                                                    int* rp0, int* rp1,
                                                    float* dinv0, float* dinv1) {
  const int* cnt = blockIdx.x ? cnt1 : cnt0;
  int* rp = blockIdx.x ? rp1 : rp0;
  float* dinv = blockIdx.x ? dinv1 : dinv0;
  __shared__ int sd[1024];
  int tid = threadIdx.x;
  int base = tid * 20;
  int pref[20];
  int run = 0;
#pragma unroll
  for (int k = 0; k < 20; k++) {
    int i = base + k;
    int c = (i < N_NODES) ? cnt[i] : 0;
    if (i < N_NODES) dinv[i] = rsqrtf((float)c + 1.0f);
    run += c;
    pref[k] = run;
  }
  sd[tid] = run;
  __syncthreads();
  for (int off = 1; off < 1024; off <<= 1) {
    int v = (tid >= off) ? sd[tid - off] : 0;
    __syncthreads();
    sd[tid] += v;
    __syncthreads();
  }
  int offset = sd[tid] - run;
  if (tid == 0) rp[0] = 0;
#pragma unroll
  for (int k = 0; k < 20; k++) {
    int i = base + k;
    if (i < N_NODES) rp[i + 1] = offset + pref[k];
  }
}

// ---------------------------------------------------------------------------
// fill (r17, kept): 512-thread blocks. First 625 blocks/branch: eg scatter
// (625*512 = 320000 exact). Last NCHUNK*4 blocks/branch: privatized t.
// grid (625 + NCHUNK*4, 2) x 512.
// ---------------------------------------------------------------------------
__global__ __launch_bounds__(512) void fill_kernel(
    const void* e0, const void* e1,
    const float* dinv0, const float* dinv1,
    const int* rp0, const int* rp1,
    const int* rank0, const int* rank1,
    unsigned int* eg0, unsigned int* eg1,
    float* t0, float* t1, const int* flags) {
  int b = blockIdx.y;
  const void* e = b ? e1 : e0;
  const float* dinv = b ? dinv1 : dinv0;
  bool w64 = flags[1] != 0;
  const int* s32 = (const int*)e;
  const int* d32 = (const int*)e + N_EDGES;
  const long long* s64 = (const long long*)e;
  const long long* d64 = (const long long*)e + N_EDGES;
  if (blockIdx.x < 625) {                 // eg-scatter role
    const int* rp = b ? rp1 : rp0;
    const int* rank = b ? rank1 : rank0;
    unsigned int* eg = b ? eg1 : eg0;
    int i = blockIdx.x * 512 + threadIdx.x;   // 625*512 = 320000 exact
    int src = w64 ? (int)s64[i] : s32[i];
    int dst = w64 ? (int)d64[i] : d32[i];
    int slot = rp[dst] + rank[i];
    eg[slot] = (unsigned int)src | ((unsigned int)f2bf(dinv[src] * dinv[dst]) << 16);
    return;
  }
  // t-accumulation role (privatized)
  float* t = b ? t1 : t0;
  int r = blockIdx.x - 625;
  int chunk = r >> 2;
  int lo = (r & 3) * NQ;
  int ebeg = chunk * (N_EDGES / NCHUNK);
  int eend = ebeg + (N_EDGES / NCHUNK);
  __shared__ float tl[NQ];
  for (int k = threadIdx.x; k < NQ; k += 512) tl[k] = 0.f;
  __syncthreads();
  for (int i = ebeg + threadIdx.x; i < eend; i += 512) {
    int src = w64 ? (int)s64[i] : s32[i];
    unsigned q = (unsigned)(src - lo);
    if (q < NQ) {
      int dst = w64 ? (int)d64[i] : d32[i];
      atomicAdd(&tl[q], dinv[dst]);
    }
  }
  __syncthreads();
  for (int k = threadIdx.x; k < NQ; k += 512) {
    float v = tl[k];
    if (v != 0.f) atomicAdd(&t[lo + k], v);   // coalesced merge, skip zeros
  }
}

// ---------------------------------------------------------------------------
// gemm (r15, verified): C[M,256] = A[M,256] @ W, B read DIRECTLY from
// precomputed Wt[n][k] bf16 (L2-broadcast). A-tile staged to LDS once,
// 1 barrier, 8 barrier-free k-steps x 8 MFMA/wave. grid (625, 1, 2).
// ---------------------------------------------------------------------------
__global__ __launch_bounds__(256) void gemm_kernel(
    const void* __restrict__ A0, const void* __restrict__ A1,
    const ushort* __restrict__ Wt,
    ushort* __restrict__ C0, ushort* __restrict__ C1,
    int maybe_f32, const int* __restrict__ flags) {
  const void* A = blockIdx.z ? A1 : A0;
  ushort* C = blockIdx.z ? C1 : C0;
  bool af32 = maybe_f32 && (flags[0] != 0);
  int m0 = blockIdx.x * 32;
  __shared__ __align__(16) ushort As[32][264];
  int tid = threadIdx.x;
  int wave = tid >> 6, lane = tid & 63;
  int quad = lane >> 4, r16 = lane & 15;
  int nb = wave * 64;             // wave's N-range
  {
    int row = tid >> 3, c0 = (tid & 7) * 32;
    int gr = m0 + row;            // always < 20000 (625*32 exact)
    if (af32) {
      const float* pA = (const float*)A + gr * 256 + c0;
      ushort* d = &As[row][c0];
#pragma unroll
      for (int s = 0; s < 8; s++) {
        float4 v = *(const float4*)(pA + s * 4);
        d[s * 4 + 0] = f2bf(v.x); d[s * 4 + 1] = f2bf(v.y);
        d[s * 4 + 2] = f2bf(v.z); d[s * 4 + 3] = f2bf(v.w);
      }
    } else {
      const ushort* pA = (const ushort*)A + gr * 256 + c0;
#pragma unroll
      for (int s = 0; s < 4; s++)
        *(int4*)&As[row][c0 + s * 8] = *(const int4*)(pA + s * 8);
    }
  }
  __syncthreads();
  f32x4 acc[2][4];
#pragma unroll
  for (int m = 0; m < 2; m++)
#pragma unroll
    for (int n = 0; n < 4; n++) acc[m][n] = (f32x4){0.f, 0.f, 0.f, 0.f};
#pragma unroll
  for (int k0 = 0; k0 < 256; k0 += 32) {
    bf16x8 a0 = *(const bf16x8*)&As[r16][k0 + quad * 8];
    bf16x8 a1 = *(const bf16x8*)&As[16 + r16][k0 + quad * 8];
    const ushort* wp = Wt + (nb + r16) * 256 + k0 + quad * 8;
    bf16x8 bb0 = *(const bf16x8*)(wp);
    bf16x8 bb1 = *(const bf16x8*)(wp + 16 * 256);
    bf16x8 bb2 = *(const bf16x8*)(wp + 32 * 256);
    bf16x8 bb3 = *(const bf16x8*)(wp + 48 * 256);
    acc[0][0] = __builtin_amdgcn_mfma_f32_16x16x32_bf16(a0, bb0, acc[0][0], 0, 0, 0);
    acc[0][1] = __builtin_amdgcn_mfma_f32_16x16x32_bf16(a0, bb1, acc[0][1], 0, 0, 0);
    acc[0][2] = __builtin_amdgcn_mfma_f32_16x16x32_bf16(a0, bb2, acc[0][2], 0, 0, 0);
    acc[0][3] = __builtin_amdgcn_mfma_f32_16x16x32_bf16(a0, bb3, acc[0][3], 0, 0, 0);
    acc[1][0] = __builtin_amdgcn_mfma_f32_16x16x32_bf16(a1, bb0, acc[1][0], 0, 0, 0);
    acc[1][1] = __builtin_amdgcn_mfma_f32_16x16x32_bf16(a1, bb1, acc[1][1], 0, 0, 0);
    acc[1][2] = __builtin_amdgcn_mfma_f32_16x16x32_bf16(a1, bb2, acc[1][2], 0, 0, 0);
    acc[1][3] = __builtin_amdgcn_mfma_f32_16x16x32_bf16(a1, bb3, acc[1][3], 0, 0, 0);
  }
#pragma unroll
  for (int m = 0; m < 2; m++) {
    int grb = m0 + m * 16 + quad * 4;
#pragma unroll
    for (int r = 0; r < 4; r++) {
      int gr = grb + r;
      ushort* cp = C + gr * 256 + nb + r16;
      cp[0]  = f2bf(acc[m][0][r]);
      cp[16] = f2bf(acc[m][1][r]);
      cp[32] = f2bf(acc[m][2][r]);
      cp[48] = f2bf(acc[m][3][r]);
    }
  }
}

// ---------------------------------------------------------------------------
// agg (r16 form, reverted from fusion): feature-sliced gather at its
// replicated ~41us plateau (r1/r14/r16 all equal). No atomics, no barrier,
// waves retire independently. r8/r9 lesson: fusing the pooled colsum via
// device-scope atomics costs +47us (cross-XCD coherence-point RMW + block
// retire barrier) -- colsum as a separate kernel was never the bottleneck.
// grid (625, 2branch, 4slice).
// ---------------------------------------------------------------------------
__global__ __launch_bounds__(256) void agg_kernel(
    const ushort* __restrict__ XW0, const ushort* __restrict__ XW1,
    const float* __restrict__ dinv0, const float* __restrict__ dinv1,
    const int* __restrict__ rp0, const int* __restrict__ rp1,
    const unsigned int* __restrict__ eg0, const unsigned int* __restrict__ eg1,
    const void* __restrict__ bias,
    ushort* __restrict__ H0, ushort* __restrict__ H1,
    const int* __restrict__ flags) {
  int b = blockIdx.y;                           // branch (middle dim)
  const ushort* XW = b ? XW1 : XW0;
  const float* dinv = b ? dinv1 : dinv0;
  const int* rp = b ? rp1 : rp0;
  const unsigned int* eg = b ? eg1 : eg0;
  ushort* H = b ? H1 : H0;
  int wave = threadIdx.x >> 6, lane = threadIdx.x & 63;
  int grp = lane >> 3;                          // node within wave (0..7)
  int fo = (lane & 7) * 8 + blockIdx.z * 64;    // slice on z
  int i = blockIdx.x * 32 + wave * 8 + grp;     // 625*32 = 20000 exact
  float di = dinv[i];
  float selfw = di * di;
  us8 v = *(const us8*)(XW + i * 256 + fo);
  float acc[8], acc2[8];
#pragma unroll
  for (int k = 0; k < 8; k++) { acc[k] = selfw * bf2f(v[k]); acc2[k] = 0.f; }
  int e = rp[i], eend = rp[i + 1];
  for (; e + 4 <= eend; e += 4) {
    unsigned int p0 = eg[e], p1 = eg[e + 1], p2 = eg[e + 2], p3 = eg[e + 3];
    us8 r0 = *(const us8*)(XW + (p0 & 0xFFFFu) * 256 + fo);
    us8 r1 = *(const us8*)(XW + (p1 & 0xFFFFu) * 256 + fo);
    us8 r2 = *(const us8*)(XW + (p2 & 0xFFFFu) * 256 + fo);
    us8 r3 = *(const us8*)(XW + (p3 & 0xFFFFu) * 256 + fo);
    float w0 = bf2f((ushort)(p0 >> 16)), w1 = bf2f((ushort)(p1 >> 16));
    float w2 = bf2f((ushort)(p2 >> 16)), w3 = bf2f((ushort)(p3 >> 16));
#pragma unroll
    for (int k = 0; k < 8; k++) {
      acc[k]  += w0 * bf2f(r0[k]);
      acc2[k] += w1 * bf2f(r1[k]);
      acc[k]  += w2 * bf2f(r2[k]);
      acc2[k] += w3 * bf2f(r3[k]);
    }
  }
  for (; e < eend; e++) {
    unsigned int pp = eg[e];
    us8 r = *(const us8*)(XW + (pp & 0xFFFFu) * 256 + fo);
    float w = bf2f((ushort)(pp >> 16));
#pragma unroll
    for (int k = 0; k < 8; k++) acc[k] += w * bf2f(r[k]);
  }
  float bv[8];
  if (flags[0]) {
    const float* bf = (const float*)bias + fo;
    float4 c0 = *(const float4*)bf;
    float4 c1 = *(const float4*)(bf + 4);
    bv[0] = c0.x; bv[1] = c0.y; bv[2] = c0.z; bv[3] = c0.w;
    bv[4] = c1.x; bv[5] = c1.y; bv[6] = c1.z; bv[7] = c1.w;
  } else {
    us8 bb = *(const us8*)((const ushort*)bias + fo);
#pragma unroll
    for (int k = 0; k < 8; k++) bv[k] = bf2f(bb[k]);
  }
  us8 o;
#pragma unroll
  for (int k = 0; k < 8; k++)
    o[k] = f2bf(fmaxf(acc[k] + acc2[k] + bv[k], 0.f));
  *(us8*)(H + i * 256 + fo) = o;
}

// Partial column sums (r7 form, restored): wave w of block handles rows
// j = (blk*4+w) + 256*k. Never a top-5 kernel.
__global__ __launch_bounds__(256) void colsum_kernel(
    const ushort* __restrict__ H0, const ushort* __restrict__ H1,
    const float* __restrict__ dinv0, const float* __restrict__ dinv1,
    const float* __restrict__ t0, const float* __restrict__ t1,
    float* __restrict__ P) {
  int b = blockIdx.y;
  const ushort* H = b ? H1 : H0;
  const float* dinv = b ? dinv1 : dinv0;
  const float* t = b ? t1 : t0;
  int wave = threadIdx.x >> 6, lane = threadIdx.x & 63;
  int wid = blockIdx.x * 4 + wave;        // 0..255
  int f4 = lane * 4;
  float a0 = 0.f, a1 = 0.f, a2 = 0.f, a3 = 0.f;
  for (int j = wid; j < N_NODES; j += 256) {
    float dj = dinv[j];
    float c = dj * (t[j] + dj);
    ushort4 u = *(const ushort4*)(H + j * 256 + f4);
    a0 += c * bf2f(u.x); a1 += c * bf2f(u.y);
    a2 += c * bf2f(u.z); a3 += c * bf2f(u.w);
  }
  __shared__ float part[4][256];
  part[wave][f4 + 0] = a0; part[wave][f4 + 1] = a1;
  part[wave][f4 + 2] = a2; part[wave][f4 + 3] = a3;
  __syncthreads();
  int f = threadIdx.x;
  float ssum = part[0][f] + part[1][f] + part[2][f] + part[3][f];
  P[(b * 64 + blockIdx.x) * 256 + f] = ssum;
}

// s = reduce partials; pooled = ((s0+s1)@W3)/(2N)+b3 ; out = pooled@Wl + bl.
__global__ __launch_bounds__(256) void final_kernel(
    const float* __restrict__ P,
    const void* __restrict__ W3, const void* __restrict__ b3,
    const void* __restrict__ Wl, const void* __restrict__ bl,
    void* __restrict__ out, const int* __restrict__ flags) {
  __shared__ float v[256];
  __shared__ float pooled[256];
  bool f32 = flags[0] != 0;
  int t = threadIdx.x;
  float acc0 = 0.f, acc1 = 0.f;
  for (int b = 0; b < 64; b++) {
    acc0 += P[b * 256 + t];
    acc1 += P[(64 + b) * 256 + t];
  }
  v[t] = acc0 + acc1;
  __syncthreads();
  float acc = 0.f;
  if (f32) {
    const float* W3f = (const float*)W3;
    for (int f = 0; f < 256; f++) acc += v[f] * W3f[f * 256 + t];
    pooled[t] = acc * (1.0f / (2.0f * N_NODES)) + ((const float*)b3)[t];
  } else {
    const ushort* W3b = (const ushort*)W3;
    for (int f = 0; f < 256; f++) acc += v[f] * bf2f(W3b[f * 256 + t]);
    pooled[t] = acc * (1.0f / (2.0f * N_NODES)) + bf2f(((const ushort*)b3)[t]);
  }
  __syncthreads();
  if (t < 5) {
    float o;
    if (f32) {
      o = ((const float*)bl)[t];
      for (int h = 0; h < 256; h++) o += pooled[h] * ((const float*)Wl)[h * 5 + t];
      ((float*)out)[t] = o;
    } else {
      o = bf2f(((const ushort*)bl)[t]);
      for (int h = 0; h < 256; h++) o += pooled[h] * bf2f(((const ushort*)Wl)[h * 5 + t]);
      ((ushort*)out)[t] = f2bf(o);
    }
  }
}

extern "C" void kernel_launch(void* const* d_in, const int* in_sizes, int n_in,
                              void* d_out, int out_size, void* d_ws, size_t ws_size,
                              hipStream_t stream) {
  const void* x1 = d_in[0];
  const void* ei1 = d_in[1];
  const void* x2 = d_in[2];
  const void* ei2 = d_in[3];
  const void* W1 = d_in[4];
  const void* b1 = d_in[5];
  const void* W2 = d_in[6];
  const void* b2 = d_in[7];
  const void* W3 = d_in[8];
  const void* b3 = d_in[9];
  const void* Wl = d_in[10];
  const void* bl = d_in[11];

  char* p = (char*)d_ws;
  auto alloc = [&](size_t bytes) {
    char* r = p;
    p += (bytes + 255) & ~size_t(255);
    return r;
  };
  int* flags   = (int*)alloc(256);
  float* dinv0 = (float*)alloc(N_NODES * 4);
  float* dinv1 = (float*)alloc(N_NODES * 4);
  float* t0    = (float*)alloc(N_NODES * 4);
  float* t1    = (float*)alloc(N_NODES * 4);
  int* cnt0    = (int*)alloc(N_NODES * 4);
  int* cnt1    = (int*)alloc(N_NODES * 4);
  int* rp0     = (int*)alloc((N_NODES + 1) * 4);
  int* rp1     = (int*)alloc((N_NODES + 1) * 4);
  unsigned int* eg0 = (unsigned int*)alloc((size_t)N_EDGES * 4);
  unsigned int* eg1 = (unsigned int*)alloc((size_t)N_EDGES * 4);
  float* Pp    = (float*)alloc(2 * 64 * 256 * 4);
  ushort* wt1  = (ushort*)alloc(256 * 256 * 2);
  ushort* wt2  = (ushort*)alloc(256 * 256 * 2);
  ushort* xw0  = (ushort*)alloc((size_t)N_NODES * HID * 2);
  ushort* xw1  = (ushort*)alloc((size_t)N_NODES * HID * 2);
  ushort* h0   = (ushort*)alloc((size_t)N_NODES * HID * 2);
  ushort* h1   = (ushort*)alloc((size_t)N_NODES * HID * 2);
  // rank aliases xw0 (rank dead after fill; xw0 first written by gemm1).
  int* rank0  = (int*)xw0;
  int* rank1  = rank0 + N_EDGES;

  // --- init+detect, wt, privatized count+rank, scan, fill ---
  init_detect_kernel<<<(N_NODES + 255) / 256 + 1, 256, 0, stream>>>(
      cnt0, cnt1, t0, t1, x1, ei1, flags);
  wt_kernel<<<512, 256, 0, stream>>>(W1, W2, wt1, wt2, flags);
  count_rank_kernel<<<dim3(NCHUNK * 4, 2), 512, 0, stream>>>(
      ei1, ei2, cnt0, cnt1, rank0, rank1, flags);
  scan_kernel<<<2, 1024, 0, stream>>>(cnt0, cnt1, rp0, rp1, dinv0, dinv1);
  fill_kernel<<<dim3(625 + NCHUNK * 4, 2), 512, 0, stream>>>(
      ei1, ei2, dinv0, dinv1, rp0, rp1, rank0, rank1, eg0, eg1, t0, t1, flags);

  // Layer 1: xw = x @ W1 ; h = relu(agg(xw) + b1)
  gemm_kernel<<<dim3(625, 1, 2), 256, 0, stream>>>(x1, x2, wt1, xw0, xw1, 1, flags);
  agg_kernel<<<dim3(625, 2, 4), 256, 0, stream>>>(
      xw0, xw1, dinv0, dinv1, rp0, rp1, eg0, eg1, b1, h0, h1, flags);

  // Layer 2: xw = h @ W2 ; h = relu(agg(xw) + b2)
  gemm_kernel<<<dim3(625, 1, 2), 256, 0, stream>>>(h0, h1, wt2, xw0, xw1, 0, flags);
  agg_kernel<<<dim3(625, 2, 4), 256, 0, stream>>>(
      xw0, xw1, dinv0, dinv1, rp0, rp1, eg0, eg1, b2, h0, h1, flags);

  // Layer 3 + pool collapsed: s = sum_j c_j h2_j ; out = ((s0+s1)W3/(2N)+b3)@Wl+bl
  colsum_kernel<<<dim3(64, 2), 256, 0, stream>>>(h0, h1, dinv0, dinv1, t0, t1, Pp);
  final_kernel<<<1, 256, 0, stream>>>(Pp, W3, b3, Wl, bl, d_out, flags);
}

// Round 15
// 351.204 us; speedup vs baseline: 1.1459x; 1.0274x over previous
//
#include <hip/hip_runtime.h>
#include <hip/hip_bf16.h>

#define N_NODES 20000
#define N_EDGES 320000
#define HID 256
#define NQ 5000          // nodes per quarter (histogram privatization)
#define NCHUNK 64        // edge chunks per branch

typedef __attribute__((ext_vector_type(8))) short bf16x8;   // 8 bf16 = 4 VGPRs (MFMA A/B frag)
typedef __attribute__((ext_vector_type(4))) float f32x4;    // MFMA C/D frag
typedef __attribute__((ext_vector_type(8))) unsigned short us8;  // 16B row chunk

__device__ __forceinline__ float bf2f(ushort u) {
  union { unsigned int i; float f; } v; v.i = ((unsigned int)u) << 16; return v.f;
}
__device__ __forceinline__ ushort f2bf(float f) {
  union { float f; unsigned int i; } v; v.f = f;
  unsigned int r = v.i + 0x7FFFu + ((v.i >> 16) & 1u);   // RNE
  return (ushort)(r >> 16);
}

// ---------------------------------------------------------------------------
// init (zero cnt/t) + runtime dtype detection fused.
// flags[0]=1 -> x/weights fp32 (else bf16). flags[1]=1 -> edges int64.
// ---------------------------------------------------------------------------
__global__ void init_detect_kernel(int* cnt0, int* cnt1, float* t0, float* t1,
                                   const void* x1, const void* ei1, int* flags) {
  if (blockIdx.x == gridDim.x - 1) {
    __shared__ int cnt_wild, cnt_oddnz;
    if (threadIdx.x == 0) { cnt_wild = 0; cnt_oddnz = 0; }
    __syncthreads();
    const ushort* xu = (const ushort*)x1;
    int wild = 0;
#pragma unroll
    for (int k = 0; k < 4; k++) {
      ushort u = xu[threadIdx.x * 4 + k];
      int ex = (u >> 7) & 0xFF;
      if (ex >= 0x90) wild++;
    }
    if (wild) atomicAdd(&cnt_wild, wild);
    const int* ii = (const int*)ei1;
    if (ii[threadIdx.x * 2 + 1] != 0) atomicAdd(&cnt_oddnz, 1);
    __syncthreads();
    if (threadIdx.x == 0) {
      flags[0] = (cnt_wild > 64) ? 1 : 0;
      flags[1] = (cnt_oddnz < 8) ? 1 : 0;
    }
    return;
  }
  int i = blockIdx.x * blockDim.x + threadIdx.x;
  if (i < N_NODES) { cnt0[i] = 0; cnt1[i] = 0; t0[i] = 0.f; t1[i] = 0.f; }
}

// ---------------------------------------------------------------------------
// wt (r15, kept): W[k][n] -> Wt[n][k] bf16, ONCE.
// ---------------------------------------------------------------------------
__global__ __launch_bounds__(256) void wt_kernel(
    const void* __restrict__ W1, const void* __restrict__ W2,
    ushort* __restrict__ Wt1, ushort* __restrict__ Wt2,
    const int* __restrict__ flags) {
  bool f32 = flags[0] != 0;
  int which = blockIdx.x >> 8;
  int k = blockIdx.x & 255;
  const void* W = which ? W2 : W1;
  ushort* Wt = which ? Wt2 : Wt1;
  int n = threadIdx.x;
  ushort v = f32 ? f2bf(((const float*)W)[k * 256 + n])
                 : ((const ushort*)W)[k * 256 + n];
  Wt[n * 256 + k] = v;
}

// ---------------------------------------------------------------------------
// countgemm (r19): count_rank AND layer-1 gemm are INDEPENDENT in the DAG
// (count needs edges; gemm1 needs x+Wt) yet were serialized: ~25us + ~35us
// + launch gap. One role-split launch overlaps them. Gemm role FIRST in the
// grid (long pole). 512 threads; LDS union: count = hist+base 40KB, gemm =
// 2 units x 32x264 ushorts = 33.8KB -> 4 blocks/CU either way.
//   blocks [0, 626): gemm role -- two independent 256-thr units per block,
//     unit handles a 32-row tile (m0 = tile*64 + unit*32), bounds-guarded
//     (313 tiles/branch x 2 branches; 313*64 = 20032 > 20000).
//   blocks [626, 1138): count role (flattened (256,2) grid).
// RACE FIX vs r14: rank no longer aliases xw0 (gemm1 writes xw0
// concurrently now) -- rank aliases h0 instead (first written by agg1,
// after fill where rank dies).
// ---------------------------------------------------------------------------
__global__ __launch_bounds__(512) void countgemm_kernel(
    const void* e0, const void* e1, int* cnt0, int* cnt1,
    int* rank0, int* rank1,
    const void* __restrict__ A0, const void* __restrict__ A1,
    const ushort* __restrict__ Wt,
    ushort* __restrict__ C0, ushort* __restrict__ C1,
    const int* __restrict__ flags) {
  __shared__ __align__(16) char smem[40960];
  if (blockIdx.x < 626) {
    // ---- gemm role ----
    int g = blockIdx.x;
    int br = (g >= 313) ? 1 : 0;
    int tile = g - 313 * br;
    const void* A = br ? A1 : A0;
    ushort* C = br ? C1 : C0;
    bool af32 = flags[0] != 0;            // layer-1 A may be fp32
    int unit = threadIdx.x >> 8;          // 0 or 1
    int t = threadIdx.x & 255;
    int m0 = tile * 64 + unit * 32;
    ushort (*As)[264] = reinterpret_cast<ushort(*)[264]>(smem + unit * 16896);
    int wave = t >> 6, lane = t & 63;
    int quad = lane >> 4, r16 = lane & 15;
    int nb = wave * 64;
    {
      int row = t >> 3, c0 = (t & 7) * 32;
      int gr = m0 + row;
      if (gr < N_NODES) {
        if (af32) {
          const float* pA = (const float*)A + gr * 256 + c0;
          ushort* d = &As[row][c0];
#pragma unroll
          for (int s = 0; s < 8; s++) {
            float4 v = *(const float4*)(pA + s * 4);
            d[s * 4 + 0] = f2bf(v.x); d[s * 4 + 1] = f2bf(v.y);
            d[s * 4 + 2] = f2bf(v.z); d[s * 4 + 3] = f2bf(v.w);
          }
        } else {
          const ushort* pA = (const ushort*)A + gr * 256 + c0;
#pragma unroll
          for (int s = 0; s < 4; s++)
            *(int4*)&As[row][c0 + s * 8] = *(const int4*)(pA + s * 8);
        }
      }
    }
    __syncthreads();
    f32x4 acc[2][4];
#pragma unroll
    for (int m = 0; m < 2; m++)
#pragma unroll
      for (int n = 0; n < 4; n++) acc[m][n] = (f32x4){0.f, 0.f, 0.f, 0.f};
#pragma unroll
    for (int k0 = 0; k0 < 256; k0 += 32) {
      bf16x8 a0 = *(const bf16x8*)&As[r16][k0 + quad * 8];
      bf16x8 a1 = *(const bf16x8*)&As[16 + r16][k0 + quad * 8];
      const ushort* wp = Wt + (nb + r16) * 256 + k0 + quad * 8;
      bf16x8 bb0 = *(const bf16x8*)(wp);
      bf16x8 bb1 = *(const bf16x8*)(wp + 16 * 256);
      bf16x8 bb2 = *(const bf16x8*)(wp + 32 * 256);
      bf16x8 bb3 = *(const bf16x8*)(wp + 48 * 256);
      acc[0][0] = __builtin_amdgcn_mfma_f32_16x16x32_bf16(a0, bb0, acc[0][0], 0, 0, 0);
      acc[0][1] = __builtin_amdgcn_mfma_f32_16x16x32_bf16(a0, bb1, acc[0][1], 0, 0, 0);
      acc[0][2] = __builtin_amdgcn_mfma_f32_16x16x32_bf16(a0, bb2, acc[0][2], 0, 0, 0);
      acc[0][3] = __builtin_amdgcn_mfma_f32_16x16x32_bf16(a0, bb3, acc[0][3], 0, 0, 0);
      acc[1][0] = __builtin_amdgcn_mfma_f32_16x16x32_bf16(a1, bb0, acc[1][0], 0, 0, 0);
      acc[1][1] = __builtin_amdgcn_mfma_f32_16x16x32_bf16(a1, bb1, acc[1][1], 0, 0, 0);
      acc[1][2] = __builtin_amdgcn_mfma_f32_16x16x32_bf16(a1, bb2, acc[1][2], 0, 0, 0);
      acc[1][3] = __builtin_amdgcn_mfma_f32_16x16x32_bf16(a1, bb3, acc[1][3], 0, 0, 0);
    }
#pragma unroll
    for (int m = 0; m < 2; m++) {
      int grb = m0 + m * 16 + quad * 4;
#pragma unroll
      for (int r = 0; r < 4; r++) {
        int gr = grb + r;
        if (gr < N_NODES) {
          ushort* cp = C + gr * 256 + nb + r16;
          cp[0]  = f2bf(acc[m][0][r]);
          cp[16] = f2bf(acc[m][1][r]);
          cp[32] = f2bf(acc[m][2][r]);
          cp[48] = f2bf(acc[m][3][r]);
        }
      }
    }
    return;
  }
  // ---- count_rank role ----
  int cb = blockIdx.x - 626;
  int b = cb >> 8;
  int x = cb & 255;
  const void* e = b ? e1 : e0;
  int* cnt = b ? cnt1 : cnt0;
  int* rank = b ? rank1 : rank0;
  int chunk = x >> 2;
  int lo = (x & 3) * NQ;
  int ebeg = chunk * (N_EDGES / NCHUNK);
  int eend = ebeg + (N_EDGES / NCHUNK);
  int* hist = (int*)smem;
  int* base = hist + NQ;
  for (int k = threadIdx.x; k < NQ; k += 512) hist[k] = 0;
  __syncthreads();
  bool w64 = flags[1] != 0;
  const int* d32 = (const int*)e + N_EDGES;
  const long long* d64 = (const long long*)e + N_EDGES;
  for (int i = ebeg + threadIdx.x; i < eend; i += 512) {
    int d = w64 ? (int)d64[i] : d32[i];
    unsigned q = (unsigned)(d - lo);
    if (q < NQ) atomicAdd(&hist[q], 1);
  }
  __syncthreads();
  for (int k = threadIdx.x; k < NQ; k += 512) {
    int h = hist[k];
    if (h) base[k] = atomicAdd(&cnt[lo + k], h);  // coalesced merge, skip zeros
    hist[k] = 0;                                  // reuse as local rank ctr
  }
  __syncthreads();
  for (int i = ebeg + threadIdx.x; i < eend; i += 512) {
    int d = w64 ? (int)d64[i] : d32[i];
    unsigned q = (unsigned)(d - lo);
    if (q < NQ) rank[i] = base[q] + atomicAdd(&hist[q], 1);
  }
}

// Exclusive scan -> CSR row_ptr, fused with dinv = rsqrt(cnt+1).
__global__ __launch_bounds__(1024) void scan_kernel(const int* cnt0, const int* cnt1,
                                                    int* rp0, int* rp1,
                                                    float* dinv0, float* dinv1) {
  const int* cnt = blockIdx.x ? cnt1 : cnt0;
  int* rp = blockIdx.x ? rp1 : rp0;
  float* dinv = blockIdx.x ? dinv1 : dinv0;
  __shared__ int sd[1024];
  int tid = threadIdx.x;
  int base = tid * 20;
  int pref[20];
  int run = 0;
#pragma unroll
  for (int k = 0; k < 20; k++) {
    int i = base + k;
    int c = (i < N_NODES) ? cnt[i] : 0;
    if (i < N_NODES) dinv[i] = rsqrtf((float)c + 1.0f);
    run += c;
    pref[k] = run;
  }
  sd[tid] = run;
  __syncthreads();
  for (int off = 1; off < 1024; off <<= 1) {
    int v = (tid >= off) ? sd[tid - off] : 0;
    __syncthreads();
    sd[tid] += v;
    __syncthreads();
  }
  int offset = sd[tid] - run;
  if (tid == 0) rp[0] = 0;
#pragma unroll
  for (int k = 0; k < 20; k++) {
    int i = base + k;
    if (i < N_NODES) rp[i + 1] = offset + pref[k];
  }
}

// ---------------------------------------------------------------------------
// fill: 512-thread blocks. First 625 blocks/branch: eg scatter (packed 4B:
// low16=src, high16=bf16(coef)) using precomputed rank -- NO atomics.
// Last NCHUNK*4 blocks/branch: t[src] += dinv[dst] via LDS float privatized
// histogram + coalesced merge (skip zeros). grid (625 + NCHUNK*4, 2) x 512.
// ---------------------------------------------------------------------------
__global__ __launch_bounds__(512) void fill_kernel(
    const void* e0, const void* e1,
    const float* dinv0, const float* dinv1,
    const int* rp0, const int* rp1,
    const int* rank0, const int* rank1,
    unsigned int* eg0, unsigned int* eg1,
    float* t0, float* t1, const int* flags) {
  int b = blockIdx.y;
  const void* e = b ? e1 : e0;
  const float* dinv = b ? dinv1 : dinv0;
  bool w64 = flags[1] != 0;
  const int* s32 = (const int*)e;
  const int* d32 = (const int*)e + N_EDGES;
  const long long* s64 = (const long long*)e;
  const long long* d64 = (const long long*)e + N_EDGES;
  if (blockIdx.x < 625) {                 // eg-scatter role
    const int* rp = b ? rp1 : rp0;
    const int* rank = b ? rank1 : rank0;
    unsigned int* eg = b ? eg1 : eg0;
    int i = blockIdx.x * 512 + threadIdx.x;   // 625*512 = 320000 exact
    int src = w64 ? (int)s64[i] : s32[i];
    int dst = w64 ? (int)d64[i] : d32[i];
    int slot = rp[dst] + rank[i];
    eg[slot] = (unsigned int)src | ((unsigned int)f2bf(dinv[src] * dinv[dst]) << 16);
    return;
  }
  // t-accumulation role (privatized)
  float* t = b ? t1 : t0;
  int r = blockIdx.x - 625;
  int chunk = r >> 2;
  int lo = (r & 3) * NQ;
  int ebeg = chunk * (N_EDGES / NCHUNK);
  int eend = ebeg + (N_EDGES / NCHUNK);
  __shared__ float tl[NQ];
  for (int k = threadIdx.x; k < NQ; k += 512) tl[k] = 0.f;
  __syncthreads();
  for (int i = ebeg + threadIdx.x; i < eend; i += 512) {
    int src = w64 ? (int)s64[i] : s32[i];
    unsigned q = (unsigned)(src - lo);
    if (q < NQ) {
      int dst = w64 ? (int)d64[i] : d32[i];
      atomicAdd(&tl[q], dinv[dst]);
    }
  }
  __syncthreads();
  for (int k = threadIdx.x; k < NQ; k += 512) {
    float v = tl[k];
    if (v != 0.f) atomicAdd(&t[lo + k], v);   // coalesced merge, skip zeros
  }
}

// ---------------------------------------------------------------------------
// gemm (r15, verified; used for layer 2 only now): C = A @ W via Wt[n][k].
// A-tile staged to LDS once, 1 barrier, 8 barrier-free k-steps. grid (625,1,2).
// ---------------------------------------------------------------------------
__global__ __launch_bounds__(256) void gemm_kernel(
    const void* __restrict__ A0, const void* __restrict__ A1,
    const ushort* __restrict__ Wt,
    ushort* __restrict__ C0, ushort* __restrict__ C1,
    int maybe_f32, const int* __restrict__ flags) {
  const void* A = blockIdx.z ? A1 : A0;
  ushort* C = blockIdx.z ? C1 : C0;
  bool af32 = maybe_f32 && (flags[0] != 0);
  int m0 = blockIdx.x * 32;
  __shared__ __align__(16) ushort As[32][264];
  int tid = threadIdx.x;
  int wave = tid >> 6, lane = tid & 63;
  int quad = lane >> 4, r16 = lane & 15;
  int nb = wave * 64;             // wave's N-range
  {
    int row = tid >> 3, c0 = (tid & 7) * 32;
    int gr = m0 + row;            // always < 20000 (625*32 exact)
    if (af32) {
      const float* pA = (const float*)A + gr * 256 + c0;
      ushort* d = &As[row][c0];
#pragma unroll
      for (int s = 0; s < 8; s++) {
        float4 v = *(const float4*)(pA + s * 4);
        d[s * 4 + 0] = f2bf(v.x); d[s * 4 + 1] = f2bf(v.y);
        d[s * 4 + 2] = f2bf(v.z); d[s * 4 + 3] = f2bf(v.w);
      }
    } else {
      const ushort* pA = (const ushort*)A + gr * 256 + c0;
#pragma unroll
      for (int s = 0; s < 4; s++)
        *(int4*)&As[row][c0 + s * 8] = *(const int4*)(pA + s * 8);
    }
  }
  __syncthreads();
  f32x4 acc[2][4];
#pragma unroll
  for (int m = 0; m < 2; m++)
#pragma unroll
    for (int n = 0; n < 4; n++) acc[m][n] = (f32x4){0.f, 0.f, 0.f, 0.f};
#pragma unroll
  for (int k0 = 0; k0 < 256; k0 += 32) {
    bf16x8 a0 = *(const bf16x8*)&As[r16][k0 + quad * 8];
    bf16x8 a1 = *(const bf16x8*)&As[16 + r16][k0 + quad * 8];
    const ushort* wp = Wt + (nb + r16) * 256 + k0 + quad * 8;
    bf16x8 bb0 = *(const bf16x8*)(wp);
    bf16x8 bb1 = *(const bf16x8*)(wp + 16 * 256);
    bf16x8 bb2 = *(const bf16x8*)(wp + 32 * 256);
    bf16x8 bb3 = *(const bf16x8*)(wp + 48 * 256);
    acc[0][0] = __builtin_amdgcn_mfma_f32_16x16x32_bf16(a0, bb0, acc[0][0], 0, 0, 0);
    acc[0][1] = __builtin_amdgcn_mfma_f32_16x16x32_bf16(a0, bb1, acc[0][1], 0, 0, 0);
    acc[0][2] = __builtin_amdgcn_mfma_f32_16x16x32_bf16(a0, bb2, acc[0][2], 0, 0, 0);
    acc[0][3] = __builtin_amdgcn_mfma_f32_16x16x32_bf16(a0, bb3, acc[0][3], 0, 0, 0);
    acc[1][0] = __builtin_amdgcn_mfma_f32_16x16x32_bf16(a1, bb0, acc[1][0], 0, 0, 0);
    acc[1][1] = __builtin_amdgcn_mfma_f32_16x16x32_bf16(a1, bb1, acc[1][1], 0, 0, 0);
    acc[1][2] = __builtin_amdgcn_mfma_f32_16x16x32_bf16(a1, bb2, acc[1][2], 0, 0, 0);
    acc[1][3] = __builtin_amdgcn_mfma_f32_16x16x32_bf16(a1, bb3, acc[1][3], 0, 0, 0);
  }
#pragma unroll
  for (int m = 0; m < 2; m++) {
    int grb = m0 + m * 16 + quad * 4;
#pragma unroll
    for (int r = 0; r < 4; r++) {
      int gr = grb + r;
      ushort* cp = C + gr * 256 + nb + r16;
      cp[0]  = f2bf(acc[m][0][r]);
      cp[16] = f2bf(acc[m][1][r]);
      cp[32] = f2bf(acc[m][2][r]);
      cp[48] = f2bf(acc[m][3][r]);
    }
  }
}

// ---------------------------------------------------------------------------
// agg (r16 form, verified): feature-sliced gather at its replicated ~41us
// plateau. No atomics, no barrier. grid (625, 2branch, 4slice).
// ---------------------------------------------------------------------------
__global__ __launch_bounds__(256) void agg_kernel(
    const ushort* __restrict__ XW0, const ushort* __restrict__ XW1,
    const float* __restrict__ dinv0, const float* __restrict__ dinv1,
    const int* __restrict__ rp0, const int* __restrict__ rp1,
    const unsigned int* __restrict__ eg0, const unsigned int* __restrict__ eg1,
    const void* __restrict__ bias,
    ushort* __restrict__ H0, ushort* __restrict__ H1,
    const int* __restrict__ flags) {
  int b = blockIdx.y;                           // branch (middle dim)
  const ushort* XW = b ? XW1 : XW0;
  const float* dinv = b ? dinv1 : dinv0;
  const int* rp = b ? rp1 : rp0;
  const unsigned int* eg = b ? eg1 : eg0;
  ushort* H = b ? H1 : H0;
  int wave = threadIdx.x >> 6, lane = threadIdx.x & 63;
  int grp = lane >> 3;                          // node within wave (0..7)
  int fo = (lane & 7) * 8 + blockIdx.z * 64;    // slice on z
  int i = blockIdx.x * 32 + wave * 8 + grp;     // 625*32 = 20000 exact
  float di = dinv[i];
  float selfw = di * di;
  us8 v = *(const us8*)(XW + i * 256 + fo);
  float acc[8], acc2[8];
#pragma unroll
  for (int k = 0; k < 8; k++) { acc[k] = selfw * bf2f(v[k]); acc2[k] = 0.f; }
  int e = rp[i], eend = rp[i + 1];
  for (; e + 4 <= eend; e += 4) {
    unsigned int p0 = eg[e], p1 = eg[e + 1], p2 = eg[e + 2], p3 = eg[e + 3];
    us8 r0 = *(const us8*)(XW + (p0 & 0xFFFFu) * 256 + fo);
    us8 r1 = *(const us8*)(XW + (p1 & 0xFFFFu) * 256 + fo);
    us8 r2 = *(const us8*)(XW + (p2 & 0xFFFFu) * 256 + fo);
    us8 r3 = *(const us8*)(XW + (p3 & 0xFFFFu) * 256 + fo);
    float w0 = bf2f((ushort)(p0 >> 16)), w1 = bf2f((ushort)(p1 >> 16));
    float w2 = bf2f((ushort)(p2 >> 16)), w3 = bf2f((ushort)(p3 >> 16));
#pragma unroll
    for (int k = 0; k < 8; k++) {
      acc[k]  += w0 * bf2f(r0[k]);
      acc2[k] += w1 * bf2f(r1[k]);
      acc[k]  += w2 * bf2f(r2[k]);
      acc2[k] += w3 * bf2f(r3[k]);
    }
  }
  for (; e < eend; e++) {
    unsigned int pp = eg[e];
    us8 r = *(const us8*)(XW + (pp & 0xFFFFu) * 256 + fo);
    float w = bf2f((ushort)(pp >> 16));
#pragma unroll
    for (int k = 0; k < 8; k++) acc[k] += w * bf2f(r[k]);
  }
  float bv[8];
  if (flags[0]) {
    const float* bf = (const float*)bias + fo;
    float4 c0 = *(const float4*)bf;
    float4 c1 = *(const float4*)(bf + 4);
    bv[0] = c0.x; bv[1] = c0.y; bv[2] = c0.z; bv[3] = c0.w;
    bv[4] = c1.x; bv[5] = c1.y; bv[6] = c1.z; bv[7] = c1.w;
  } else {
    us8 bb = *(const us8*)((const ushort*)bias + fo);
#pragma unroll
    for (int k = 0; k < 8; k++) bv[k] = bf2f(bb[k]);
  }
  us8 o;
#pragma unroll
  for (int k = 0; k < 8; k++)
    o[k] = f2bf(fmaxf(acc[k] + acc2[k] + bv[k], 0.f));
  *(us8*)(H + i * 256 + fo) = o;
}

// Partial column sums: wave w of block handles rows j = (blk*4+w) + 256*k.
__global__ __launch_bounds__(256) void colsum_kernel(
    const ushort* __restrict__ H0, const ushort* __restrict__ H1,
    const float* __restrict__ dinv0, const float* __restrict__ dinv1,
    const float* __restrict__ t0, const float* __restrict__ t1,
    float* __restrict__ P) {
  int b = blockIdx.y;
  const ushort* H = b ? H1 : H0;
  const float* dinv = b ? dinv1 : dinv0;
  const float* t = b ? t1 : t0;
  int wave = threadIdx.x >> 6, lane = threadIdx.x & 63;
  int wid = blockIdx.x * 4 + wave;        // 0..255
  int f4 = lane * 4;
  float a0 = 0.f, a1 = 0.f, a2 = 0.f, a3 = 0.f;
  for (int j = wid; j < N_NODES; j += 256) {
    float dj = dinv[j];
    float c = dj * (t[j] + dj);
    ushort4 u = *(const ushort4*)(H + j * 256 + f4);
    a0 += c * bf2f(u.x); a1 += c * bf2f(u.y);
    a2 += c * bf2f(u.z); a3 += c * bf2f(u.w);
  }
  __shared__ float part[4][256];
  part[wave][f4 + 0] = a0; part[wave][f4 + 1] = a1;
  part[wave][f4 + 2] = a2; part[wave][f4 + 3] = a3;
  __syncthreads();
  int f = threadIdx.x;
  float ssum = part[0][f] + part[1][f] + part[2][f] + part[3][f];
  P[(b * 64 + blockIdx.x) * 256 + f] = ssum;
}

// s = reduce partials; pooled = ((s0+s1)@W3)/(2N)+b3 ; out = pooled@Wl + bl.
__global__ __launch_bounds__(256) void final_kernel(
    const float* __restrict__ P,
    const void* __restrict__ W3, const void* __restrict__ b3,
    const void* __restrict__ Wl, const void* __restrict__ bl,
    void* __restrict__ out, const int* __restrict__ flags) {
  __shared__ float v[256];
  __shared__ float pooled[256];
  bool f32 = flags[0] != 0;
  int t = threadIdx.x;
  float acc0 = 0.f, acc1 = 0.f;
  for (int b = 0; b < 64; b++) {
    acc0 += P[b * 256 + t];
    acc1 += P[(64 + b) * 256 + t];
  }
  v[t] = acc0 + acc1;
  __syncthreads();
  float acc = 0.f;
  if (f32) {
    const float* W3f = (const float*)W3;
    for (int f = 0; f < 256; f++) acc += v[f] * W3f[f * 256 + t];
    pooled[t] = acc * (1.0f / (2.0f * N_NODES)) + ((const float*)b3)[t];
  } else {
    const ushort* W3b = (const ushort*)W3;
    for (int f = 0; f < 256; f++) acc += v[f] * bf2f(W3b[f * 256 + t]);
    pooled[t] = acc * (1.0f / (2.0f * N_NODES)) + bf2f(((const ushort*)b3)[t]);
  }
  __syncthreads();
  if (t < 5) {
    float o;
    if (f32) {
      o = ((const float*)bl)[t];
      for (int h = 0; h < 256; h++) o += pooled[h] * ((const float*)Wl)[h * 5 + t];
      ((float*)out)[t] = o;
    } else {
      o = bf2f(((const ushort*)bl)[t]);
      for (int h = 0; h < 256; h++) o += pooled[h] * bf2f(((const ushort*)Wl)[h * 5 + t]);
      ((ushort*)out)[t] = f2bf(o);
    }
  }
}

extern "C" void kernel_launch(void* const* d_in, const int* in_sizes, int n_in,
                              void* d_out, int out_size, void* d_ws, size_t ws_size,
                              hipStream_t stream) {
  const void* x1 = d_in[0];
  const void* ei1 = d_in[1];
  const void* x2 = d_in[2];
  const void* ei2 = d_in[3];
  const void* W1 = d_in[4];
  const void* b1 = d_in[5];
  const void* W2 = d_in[6];
  const void* b2 = d_in[7];
  const void* W3 = d_in[8];
  const void* b3 = d_in[9];
  const void* Wl = d_in[10];
  const void* bl = d_in[11];

  char* p = (char*)d_ws;
  auto alloc = [&](size_t bytes) {
    char* r = p;
    p += (bytes + 255) & ~size_t(255);
    return r;
  };
  int* flags   = (int*)alloc(256);
  float* dinv0 = (float*)alloc(N_NODES * 4);
  float* dinv1 = (float*)alloc(N_NODES * 4);
  float* t0    = (float*)alloc(N_NODES * 4);
  float* t1    = (float*)alloc(N_NODES * 4);
  int* cnt0    = (int*)alloc(N_NODES * 4);
  int* cnt1    = (int*)alloc(N_NODES * 4);
  int* rp0     = (int*)alloc((N_NODES + 1) * 4);
  int* rp1     = (int*)alloc((N_NODES + 1) * 4);
  unsigned int* eg0 = (unsigned int*)alloc((size_t)N_EDGES * 4);
  unsigned int* eg1 = (unsigned int*)alloc((size_t)N_EDGES * 4);
  float* Pp    = (float*)alloc(2 * 64 * 256 * 4);
  ushort* wt1  = (ushort*)alloc(256 * 256 * 2);
  ushort* wt2  = (ushort*)alloc(256 * 256 * 2);
  ushort* xw0  = (ushort*)alloc((size_t)N_NODES * HID * 2);
  ushort* xw1  = (ushort*)alloc((size_t)N_NODES * HID * 2);
  ushort* h0   = (ushort*)alloc((size_t)N_NODES * HID * 2);
  ushort* h1   = (ushort*)alloc((size_t)N_NODES * HID * 2);
  // rank aliases h0 (NOT xw0: gemm1 now runs concurrent with count_rank in
  // countgemm and writes xw0). rank dead after fill; h0 first written by
  // agg1 which runs after fill. 2*320000*4 = 2.56MB <= 10.24MB.
  int* rank0  = (int*)h0;
  int* rank1  = rank0 + N_EDGES;

  // init+detect, wt
  init_detect_kernel<<<(N_NODES + 255) / 256 + 1, 256, 0, stream>>>(
      cnt0, cnt1, t0, t1, x1, ei1, flags);
  wt_kernel<<<512, 256, 0, stream>>>(W1, W2, wt1, wt2, flags);

  // OVERLAPPED: layer-1 gemm (xw = x @ W1) || count_rank  (independent DAG arms)
  countgemm_kernel<<<626 + 512, 512, 0, stream>>>(
      ei1, ei2, cnt0, cnt1, rank0, rank1,
      x1, x2, wt1, xw0, xw1, flags);

  scan_kernel<<<2, 1024, 0, stream>>>(cnt0, cnt1, rp0, rp1, dinv0, dinv1);
  fill_kernel<<<dim3(625 + NCHUNK * 4, 2), 512, 0, stream>>>(
      ei1, ei2, dinv0, dinv1, rp0, rp1, rank0, rank1, eg0, eg1, t0, t1, flags);

  // Layer 1 aggregate: h = relu(agg(xw) + b1)
  agg_kernel<<<dim3(625, 2, 4), 256, 0, stream>>>(
      xw0, xw1, dinv0, dinv1, rp0, rp1, eg0, eg1, b1, h0, h1, flags);

  // Layer 2: xw = h @ W2 ; h = relu(agg(xw) + b2)
  gemm_kernel<<<dim3(625, 1, 2), 256, 0, stream>>>(h0, h1, wt2, xw0, xw1, 0, flags);
  agg_kernel<<<dim3(625, 2, 4), 256, 0, stream>>>(
      xw0, xw1, dinv0, dinv1, rp0, rp1, eg0, eg1, b2, h0, h1, flags);

  // Layer 3 + pool collapsed: s = sum_j c_j h2_j ; out = ((s0+s1)W3/(2N)+b3)@Wl+bl
  colsum_kernel<<<dim3(64, 2), 256, 0, stream>>>(h0, h1, dinv0, dinv1, t0, t1, Pp);
  final_kernel<<<1, 256, 0, stream>>>(Pp, W3, b3, Wl, bl, d_out, flags);
}

// Round 17
// 350.295 us; speedup vs baseline: 1.1489x; 1.0026x over previous
//
#include <hip/hip_runtime.h>
#include <hip/hip_bf16.h>

#define N_NODES 20000
#define N_EDGES 320000
#define HID 256
#define NQ 5000          // nodes per quarter (histogram privatization)
#define NCHUNK 64        // edge chunks per branch

typedef __attribute__((ext_vector_type(8))) short bf16x8;   // 8 bf16 = 4 VGPRs (MFMA A/B frag)
typedef __attribute__((ext_vector_type(4))) float f32x4;    // MFMA C/D frag
typedef __attribute__((ext_vector_type(8))) unsigned short us8;  // 16B row chunk

__device__ __forceinline__ float bf2f(ushort u) {
  union { unsigned int i; float f; } v; v.i = ((unsigned int)u) << 16; return v.f;
}
__device__ __forceinline__ ushort f2bf(float f) {
  union { float f; unsigned int i; } v; v.f = f;
  unsigned int r = v.i + 0x7FFFu + ((v.i >> 16) & 1u);   // RNE
  return (ushort)(r >> 16);
}

// ---------------------------------------------------------------------------
// Shared role bodies (device functions) -- byte-identical logic to the
// verified kernels; reused by the two overlap launches.
// ---------------------------------------------------------------------------
__device__ __forceinline__ void gemm_role(
    char* smem, int tile, const void* __restrict__ A, ushort* __restrict__ C,
    bool af32, const ushort* __restrict__ Wt) {
  int unit = threadIdx.x >> 8;          // 0 or 1
  int t = threadIdx.x & 255;
  int m0 = tile * 64 + unit * 32;
  ushort (*As)[264] = reinterpret_cast<ushort(*)[264]>(smem + unit * 16896);
  int wave = t >> 6, lane = t & 63;
  int quad = lane >> 4, r16 = lane & 15;
  int nb = wave * 64;
  {
    int row = t >> 3, c0 = (t & 7) * 32;
    int gr = m0 + row;
    if (gr < N_NODES) {
      if (af32) {
        const float* pA = (const float*)A + gr * 256 + c0;
        ushort* d = &As[row][c0];
#pragma unroll
        for (int s = 0; s < 8; s++) {
          float4 v = *(const float4*)(pA + s * 4);
          d[s * 4 + 0] = f2bf(v.x); d[s * 4 + 1] = f2bf(v.y);
          d[s * 4 + 2] = f2bf(v.z); d[s * 4 + 3] = f2bf(v.w);
        }
      } else {
        const ushort* pA = (const ushort*)A + gr * 256 + c0;
#pragma unroll
        for (int s = 0; s < 4; s++)
          *(int4*)&As[row][c0 + s * 8] = *(const int4*)(pA + s * 8);
      }
    }
  }
  __syncthreads();
  f32x4 acc[2][4];
#pragma unroll
  for (int m = 0; m < 2; m++)
#pragma unroll
    for (int n = 0; n < 4; n++) acc[m][n] = (f32x4){0.f, 0.f, 0.f, 0.f};
#pragma unroll
  for (int k0 = 0; k0 < 256; k0 += 32) {
    bf16x8 a0 = *(const bf16x8*)&As[r16][k0 + quad * 8];
    bf16x8 a1 = *(const bf16x8*)&As[16 + r16][k0 + quad * 8];
    const ushort* wp = Wt + (nb + r16) * 256 + k0 + quad * 8;
    bf16x8 bb0 = *(const bf16x8*)(wp);
    bf16x8 bb1 = *(const bf16x8*)(wp + 16 * 256);
    bf16x8 bb2 = *(const bf16x8*)(wp + 32 * 256);
    bf16x8 bb3 = *(const bf16x8*)(wp + 48 * 256);
    acc[0][0] = __builtin_amdgcn_mfma_f32_16x16x32_bf16(a0, bb0, acc[0][0], 0, 0, 0);
    acc[0][1] = __builtin_amdgcn_mfma_f32_16x16x32_bf16(a0, bb1, acc[0][1], 0, 0, 0);
    acc[0][2] = __builtin_amdgcn_mfma_f32_16x16x32_bf16(a0, bb2, acc[0][2], 0, 0, 0);
    acc[0][3] = __builtin_amdgcn_mfma_f32_16x16x32_bf16(a0, bb3, acc[0][3], 0, 0, 0);
    acc[1][0] = __builtin_amdgcn_mfma_f32_16x16x32_bf16(a1, bb0, acc[1][0], 0, 0, 0);
    acc[1][1] = __builtin_amdgcn_mfma_f32_16x16x32_bf16(a1, bb1, acc[1][1], 0, 0, 0);
    acc[1][2] = __builtin_amdgcn_mfma_f32_16x16x32_bf16(a1, bb2, acc[1][2], 0, 0, 0);
    acc[1][3] = __builtin_amdgcn_mfma_f32_16x16x32_bf16(a1, bb3, acc[1][3], 0, 0, 0);
  }
#pragma unroll
  for (int m = 0; m < 2; m++) {
    int grb = m0 + m * 16 + quad * 4;
#pragma unroll
    for (int r = 0; r < 4; r++) {
      int gr = grb + r;
      if (gr < N_NODES) {
        ushort* cp = C + gr * 256 + nb + r16;
        cp[0]  = f2bf(acc[m][0][r]);
        cp[16] = f2bf(acc[m][1][r]);
        cp[32] = f2bf(acc[m][2][r]);
        cp[48] = f2bf(acc[m][3][r]);
      }
    }
  }
}

// ---------------------------------------------------------------------------
// init (zero cnt/t) + runtime dtype detection fused.
// flags[0]=1 -> x/weights fp32 (else bf16). flags[1]=1 -> edges int64.
// ---------------------------------------------------------------------------
__global__ void init_detect_kernel(int* cnt0, int* cnt1, float* t0, float* t1,
                                   const void* x1, const void* ei1, int* flags) {
  if (blockIdx.x == gridDim.x - 1) {
    __shared__ int cnt_wild, cnt_oddnz;
    if (threadIdx.x == 0) { cnt_wild = 0; cnt_oddnz = 0; }
    __syncthreads();
    const ushort* xu = (const ushort*)x1;
    int wild = 0;
#pragma unroll
    for (int k = 0; k < 4; k++) {
      ushort u = xu[threadIdx.x * 4 + k];
      int ex = (u >> 7) & 0xFF;
      if (ex >= 0x90) wild++;
    }
    if (wild) atomicAdd(&cnt_wild, wild);
    const int* ii = (const int*)ei1;
    if (ii[threadIdx.x * 2 + 1] != 0) atomicAdd(&cnt_oddnz, 1);
    __syncthreads();
    if (threadIdx.x == 0) {
      flags[0] = (cnt_wild > 64) ? 1 : 0;
      flags[1] = (cnt_oddnz < 8) ? 1 : 0;
    }
    return;
  }
  int i = blockIdx.x * blockDim.x + threadIdx.x;
  if (i < N_NODES) { cnt0[i] = 0; cnt1[i] = 0; t0[i] = 0.f; t1[i] = 0.f; }
}

// ---------------------------------------------------------------------------
// wt: W[k][n] -> Wt[n][k] bf16, ONCE.
// ---------------------------------------------------------------------------
__global__ __launch_bounds__(256) void wt_kernel(
    const void* __restrict__ W1, const void* __restrict__ W2,
    ushort* __restrict__ Wt1, ushort* __restrict__ Wt2,
    const int* __restrict__ flags) {
  bool f32 = flags[0] != 0;
  int which = blockIdx.x >> 8;
  int k = blockIdx.x & 255;
  const void* W = which ? W2 : W1;
  ushort* Wt = which ? Wt2 : Wt1;
  int n = threadIdx.x;
  ushort v = f32 ? f2bf(((const float*)W)[k * 256 + n])
                 : ((const ushort*)W)[k * 256 + n];
  Wt[n * 256 + k] = v;
}

// ---------------------------------------------------------------------------
// countgemm (r20): count_rank + gemm1-BRANCH0 only (825 blocks -- fits one
// 1024-block residency wave, killing r15's 114-block tail). gemm role first.
// ---------------------------------------------------------------------------
__global__ __launch_bounds__(512) void countgemm_kernel(
    const void* e0, const void* e1, int* cnt0, int* cnt1,
    int* rank0, int* rank1,
    const void* __restrict__ A0,
    const ushort* __restrict__ Wt,
    ushort* __restrict__ C0,
    const int* __restrict__ flags) {
  __shared__ __align__(16) char smem[40960];
  if (blockIdx.x < 313) {
    gemm_role(smem, blockIdx.x, A0, C0, flags[0] != 0, Wt);
    return;
  }
  // ---- count_rank role ----
  int cb = blockIdx.x - 313;
  int b = cb >> 8;
  int x = cb & 255;
  const void* e = b ? e1 : e0;
  int* cnt = b ? cnt1 : cnt0;
  int* rank = b ? rank1 : rank0;
  int chunk = x >> 2;
  int lo = (x & 3) * NQ;
  int ebeg = chunk * (N_EDGES / NCHUNK);
  int eend = ebeg + (N_EDGES / NCHUNK);
  int* hist = (int*)smem;
  int* base = hist + NQ;
  for (int k = threadIdx.x; k < NQ; k += 512) hist[k] = 0;
  __syncthreads();
  bool w64 = flags[1] != 0;
  const int* d32 = (const int*)e + N_EDGES;
  const long long* d64 = (const long long*)e + N_EDGES;
  for (int i = ebeg + threadIdx.x; i < eend; i += 512) {
    int d = w64 ? (int)d64[i] : d32[i];
    unsigned q = (unsigned)(d - lo);
    if (q < NQ) atomicAdd(&hist[q], 1);
  }
  __syncthreads();
  for (int k = threadIdx.x; k < NQ; k += 512) {
    int h = hist[k];
    if (h) base[k] = atomicAdd(&cnt[lo + k], h);  // coalesced merge, skip zeros
    hist[k] = 0;                                  // reuse as local rank ctr
  }
  __syncthreads();
  for (int i = ebeg + threadIdx.x; i < eend; i += 512) {
    int d = w64 ? (int)d64[i] : d32[i];
    unsigned q = (unsigned)(d - lo);
    if (q < NQ) rank[i] = base[q] + atomicAdd(&hist[q], 1);
  }
}

// Exclusive scan -> CSR row_ptr, fused with dinv = rsqrt(cnt+1).
__global__ __launch_bounds__(1024) void scan_kernel(const int* cnt0, const int* cnt1,
                                                    int* rp0, int* rp1,
                                                    float* dinv0, float* dinv1) {
  const int* cnt = blockIdx.x ? cnt1 : cnt0;
  int* rp = blockIdx.x ? rp1 : rp0;
  float* dinv = blockIdx.x ? dinv1 : dinv0;
  __shared__ int sd[1024];
  int tid = threadIdx.x;
  int base = tid * 20;
  int pref[20];
  int run = 0;
#pragma unroll
  for (int k = 0; k < 20; k++) {
    int i = base + k;
    int c = (i < N_NODES) ? cnt[i] : 0;
    if (i < N_NODES) dinv[i] = rsqrtf((float)c + 1.0f);
    run += c;
    pref[k] = run;
  }
  sd[tid] = run;
  __syncthreads();
  for (int off = 1; off < 1024; off <<= 1) {
    int v = (tid >= off) ? sd[tid - off] : 0;
    __syncthreads();
    sd[tid] += v;
    __syncthreads();
  }
  int offset = sd[tid] - run;
  if (tid == 0) rp[0] = 0;
#pragma unroll
  for (int k = 0; k < 20; k++) {
    int i = base + k;
    if (i < N_NODES) rp[i + 1] = offset + pref[k];
  }
}

// ---------------------------------------------------------------------------
// fillgemm (r20): fill (both roles) + gemm1-BRANCH1 overlapped.
//   [0, 313): gemm role branch1.
//   [313, 1563): eg-scatter role (sb -> (branch, 512-edge chunk)).
//   [1563, 2075): privatized-t role.
// Races: gemm writes xw1; scatter reads rank(h0)/rp/dinv, writes eg;
// t-role reads edges/dinv, writes t via atomics. All disjoint.
// ---------------------------------------------------------------------------
__global__ __launch_bounds__(512) void fillgemm_kernel(
    const void* e0, const void* e1,
    const float* dinv0, const float* dinv1,
    const int* rp0, const int* rp1,
    const int* rank0, const int* rank1,
    unsigned int* eg0, unsigned int* eg1,
    float* t0, float* t1,
    const void* __restrict__ A1,
    const ushort* __restrict__ Wt,
    ushort* __restrict__ C1,
    const int* __restrict__ flags) {
  __shared__ __align__(16) char smem[40960];
  if (blockIdx.x < 313) {
    gemm_role(smem, blockIdx.x, A1, C1, flags[0] != 0, Wt);
    return;
  }
  bool w64 = flags[1] != 0;
  if (blockIdx.x < 1563) {                // eg-scatter role
    int sb = blockIdx.x - 313;
    int b = (sb >= 625) ? 1 : 0;
    int blk = sb - 625 * b;
    const void* e = b ? e1 : e0;
    const float* dinv = b ? dinv1 : dinv0;
    const int* rp = b ? rp1 : rp0;
    const int* rank = b ? rank1 : rank0;
    unsigned int* eg = b ? eg1 : eg0;
    const int* s32 = (const int*)e;
    const int* d32 = (const int*)e + N_EDGES;
    const long long* s64 = (const long long*)e;
    const long long* d64 = (const long long*)e + N_EDGES;
    int i = blk * 512 + threadIdx.x;      // 625*512 = 320000 exact
    int src = w64 ? (int)s64[i] : s32[i];
    int dst = w64 ? (int)d64[i] : d32[i];
    int slot = rp[dst] + rank[i];
    eg[slot] = (unsigned int)src | ((unsigned int)f2bf(dinv[src] * dinv[dst]) << 16);
    return;
  }
  // ---- privatized-t role ----
  int r = blockIdx.x - 1563;
  int b = r >> 8;
  int rr = r & 255;
  const void* e = b ? e1 : e0;
  const float* dinv = b ? dinv1 : dinv0;
  float* t = b ? t1 : t0;
  const int* s32 = (const int*)e;
  const int* d32 = (const int*)e + N_EDGES;
  const long long* s64 = (const long long*)e;
  const long long* d64 = (const long long*)e + N_EDGES;
  int chunk = rr >> 2;
  int lo = (rr & 3) * NQ;
  int ebeg = chunk * (N_EDGES / NCHUNK);
  int eend = ebeg + (N_EDGES / NCHUNK);
  float* tl = (float*)smem;
  for (int k = threadIdx.x; k < NQ; k += 512) tl[k] = 0.f;
  __syncthreads();
  for (int i = ebeg + threadIdx.x; i < eend; i += 512) {
    int src = w64 ? (int)s64[i] : s32[i];
    unsigned q = (unsigned)(src - lo);
    if (q < NQ) {
      int dst = w64 ? (int)d64[i] : d32[i];
      atomicAdd(&tl[q], dinv[dst]);
    }
  }
  __syncthreads();
  for (int k = threadIdx.x; k < NQ; k += 512) {
    float v = tl[k];
    if (v != 0.f) atomicAdd(&t[lo + k], v);   // coalesced merge, skip zeros
  }
}

// ---------------------------------------------------------------------------
// gemm (r15, verified; layer 2): C = A @ W via Wt[n][k]. grid (625,1,2).
// ---------------------------------------------------------------------------
__global__ __launch_bounds__(256) void gemm_kernel(
    const void* __restrict__ A0, const void* __restrict__ A1,
    const ushort* __restrict__ Wt,
    ushort* __restrict__ C0, ushort* __restrict__ C1,
    int maybe_f32, const int* __restrict__ flags) {
  const void* A = blockIdx.z ? A1 : A0;
  ushort* C = blockIdx.z ? C1 : C0;
  bool af32 = maybe_f32 && (flags[0] != 0);
  int m0 = blockIdx.x * 32;
  __shared__ __align__(16) ushort As[32][264];
  int tid = threadIdx.x;
  int wave = tid >> 6, lane = tid & 63;
  int quad = lane >> 4, r16 = lane & 15;
  int nb = wave * 64;             // wave's N-range
  {
    int row = tid >> 3, c0 = (tid & 7) * 32;
    int gr = m0 + row;            // always < 20000 (625*32 exact)
    if (af32) {
      const float* pA = (const float*)A + gr * 256 + c0;
      ushort* d = &As[row][c0];
#pragma unroll
      for (int s = 0; s < 8; s++) {
        float4 v = *(const float4*)(pA + s * 4);
        d[s * 4 + 0] = f2bf(v.x); d[s * 4 + 1] = f2bf(v.y);
        d[s * 4 + 2] = f2bf(v.z); d[s * 4 + 3] = f2bf(v.w);
      }
    } else {
      const ushort* pA = (const ushort*)A + gr * 256 + c0;
#pragma unroll
      for (int s = 0; s < 4; s++)
        *(int4*)&As[row][c0 + s * 8] = *(const int4*)(pA + s * 8);
    }
  }
  __syncthreads();
  f32x4 acc[2][4];
#pragma unroll
  for (int m = 0; m < 2; m++)
#pragma unroll
    for (int n = 0; n < 4; n++) acc[m][n] = (f32x4){0.f, 0.f, 0.f, 0.f};
#pragma unroll
  for (int k0 = 0; k0 < 256; k0 += 32) {
    bf16x8 a0 = *(const bf16x8*)&As[r16][k0 + quad * 8];
    bf16x8 a1 = *(const bf16x8*)&As[16 + r16][k0 + quad * 8];
    const ushort* wp = Wt + (nb + r16) * 256 + k0 + quad * 8;
    bf16x8 bb0 = *(const bf16x8*)(wp);
    bf16x8 bb1 = *(const bf16x8*)(wp + 16 * 256);
    bf16x8 bb2 = *(const bf16x8*)(wp + 32 * 256);
    bf16x8 bb3 = *(const bf16x8*)(wp + 48 * 256);
    acc[0][0] = __builtin_amdgcn_mfma_f32_16x16x32_bf16(a0, bb0, acc[0][0], 0, 0, 0);
    acc[0][1] = __builtin_amdgcn_mfma_f32_16x16x32_bf16(a0, bb1, acc[0][1], 0, 0, 0);
    acc[0][2] = __builtin_amdgcn_mfma_f32_16x16x32_bf16(a0, bb2, acc[0][2], 0, 0, 0);
    acc[0][3] = __builtin_amdgcn_mfma_f32_16x16x32_bf16(a0, bb3, acc[0][3], 0, 0, 0);
    acc[1][0] = __builtin_amdgcn_mfma_f32_16x16x32_bf16(a1, bb0, acc[1][0], 0, 0, 0);
    acc[1][1] = __builtin_amdgcn_mfma_f32_16x16x32_bf16(a1, bb1, acc[1][1], 0, 0, 0);
    acc[1][2] = __builtin_amdgcn_mfma_f32_16x16x32_bf16(a1, bb2, acc[1][2], 0, 0, 0);
    acc[1][3] = __builtin_amdgcn_mfma_f32_16x16x32_bf16(a1, bb3, acc[1][3], 0, 0, 0);
  }
#pragma unroll
  for (int m = 0; m < 2; m++) {
    int grb = m0 + m * 16 + quad * 4;
#pragma unroll
    for (int r = 0; r < 4; r++) {
      int gr = grb + r;
      ushort* cp = C + gr * 256 + nb + r16;
      cp[0]  = f2bf(acc[m][0][r]);
      cp[16] = f2bf(acc[m][1][r]);
      cp[32] = f2bf(acc[m][2][r]);
      cp[48] = f2bf(acc[m][3][r]);
    }
  }
}

// ---------------------------------------------------------------------------
// agg (r16 form, verified): feature-sliced gather at its replicated ~41us
// plateau. No atomics, no barrier. grid (625, 2branch, 4slice).
// ---------------------------------------------------------------------------
__global__ __launch_bounds__(256) void agg_kernel(
    const ushort* __restrict__ XW0, const ushort* __restrict__ XW1,
    const float* __restrict__ dinv0, const float* __restrict__ dinv1,
    const int* __restrict__ rp0, const int* __restrict__ rp1,
    const unsigned int* __restrict__ eg0, const unsigned int* __restrict__ eg1,
    const void* __restrict__ bias,
    ushort* __restrict__ H0, ushort* __restrict__ H1,
    const int* __restrict__ flags) {
  int b = blockIdx.y;                           // branch (middle dim)
  const ushort* XW = b ? XW1 : XW0;
  const float* dinv = b ? dinv1 : dinv0;
  const int* rp = b ? rp1 : rp0;
  const unsigned int* eg = b ? eg1 : eg0;
  ushort* H = b ? H1 : H0;
  int wave = threadIdx.x >> 6, lane = threadIdx.x & 63;
  int grp = lane >> 3;                          // node within wave (0..7)
  int fo = (lane & 7) * 8 + blockIdx.z * 64;    // slice on z
  int i = blockIdx.x * 32 + wave * 8 + grp;     // 625*32 = 20000 exact
  float di = dinv[i];
  float selfw = di * di;
  us8 v = *(const us8*)(XW + i * 256 + fo);
  float acc[8], acc2[8];
#pragma unroll
  for (int k = 0; k < 8; k++) { acc[k] = selfw * bf2f(v[k]); acc2[k] = 0.f; }
  int e = rp[i], eend = rp[i + 1];
  for (; e + 4 <= eend; e += 4) {
    unsigned int p0 = eg[e], p1 = eg[e + 1], p2 = eg[e + 2], p3 = eg[e + 3];
    us8 r0 = *(const us8*)(XW + (p0 & 0xFFFFu) * 256 + fo);
    us8 r1 = *(const us8*)(XW + (p1 & 0xFFFFu) * 256 + fo);
    us8 r2 = *(const us8*)(XW + (p2 & 0xFFFFu) * 256 + fo);
    us8 r3 = *(const us8*)(XW + (p3 & 0xFFFFu) * 256 + fo);
    float w0 = bf2f((ushort)(p0 >> 16)), w1 = bf2f((ushort)(p1 >> 16));
    float w2 = bf2f((ushort)(p2 >> 16)), w3 = bf2f((ushort)(p3 >> 16));
#pragma unroll
    for (int k = 0; k < 8; k++) {
      acc[k]  += w0 * bf2f(r0[k]);
      acc2[k] += w1 * bf2f(r1[k]);
      acc[k]  += w2 * bf2f(r2[k]);
      acc2[k] += w3 * bf2f(r3[k]);
    }
  }
  for (; e < eend; e++) {
    unsigned int pp = eg[e];
    us8 r = *(const us8*)(XW + (pp & 0xFFFFu) * 256 + fo);
    float w = bf2f((ushort)(pp >> 16));
#pragma unroll
    for (int k = 0; k < 8; k++) acc[k] += w * bf2f(r[k]);
  }
  float bv[8];
  if (flags[0]) {
    const float* bf = (const float*)bias + fo;
    float4 c0 = *(const float4*)bf;
    float4 c1 = *(const float4*)(bf + 4);
    bv[0] = c0.x; bv[1] = c0.y; bv[2] = c0.z; bv[3] = c0.w;
    bv[4] = c1.x; bv[5] = c1.y; bv[6] = c1.z; bv[7] = c1.w;
  } else {
    us8 bb = *(const us8*)((const ushort*)bias + fo);
#pragma unroll
    for (int k = 0; k < 8; k++) bv[k] = bf2f(bb[k]);
  }
  us8 o;
#pragma unroll
  for (int k = 0; k < 8; k++)
    o[k] = f2bf(fmaxf(acc[k] + acc2[k] + bv[k], 0.f));
  *(us8*)(H + i * 256 + fo) = o;
}

// Partial column sums: wave w of block handles rows j = (blk*4+w) + 256*k.
__global__ __launch_bounds__(256) void colsum_kernel(
    const ushort* __restrict__ H0, const ushort* __restrict__ H1,
    const float* __restrict__ dinv0, const float* __restrict__ dinv1,
    const float* __restrict__ t0, const float* __restrict__ t1,
    float* __restrict__ P) {
  int b = blockIdx.y;
  const ushort* H = b ? H1 : H0;
  const float* dinv = b ? dinv1 : dinv0;
  const float* t = b ? t1 : t0;
  int wave = threadIdx.x >> 6, lane = threadIdx.x & 63;
  int wid = blockIdx.x * 4 + wave;        // 0..255
  int f4 = lane * 4;
  float a0 = 0.f, a1 = 0.f, a2 = 0.f, a3 = 0.f;
  for (int j = wid; j < N_NODES; j += 256) {
    float dj = dinv[j];
    float c = dj * (t[j] + dj);
    ushort4 u = *(const ushort4*)(H + j * 256 + f4);
    a0 += c * bf2f(u.x); a1 += c * bf2f(u.y);
    a2 += c * bf2f(u.z); a3 += c * bf2f(u.w);
  }
  __shared__ float part[4][256];
  part[wave][f4 + 0] = a0; part[wave][f4 + 1] = a1;
  part[wave][f4 + 2] = a2; part[wave][f4 + 3] = a3;
  __syncthreads();
  int f = threadIdx.x;
  float ssum = part[0][f] + part[1][f] + part[2][f] + part[3][f];
  P[(b * 64 + blockIdx.x) * 256 + f] = ssum;
}

// s = reduce partials; pooled = ((s0+s1)@W3)/(2N)+b3 ; out = pooled@Wl + bl.
__global__ __launch_bounds__(256) void final_kernel(
    const float* __restrict__ P,
    const void* __restrict__ W3, const void* __restrict__ b3,
    const void* __restrict__ Wl, const void* __restrict__ bl,
    void* __restrict__ out, const int* __restrict__ flags) {
  __shared__ float v[256];
  __shared__ float pooled[256];
  bool f32 = flags[0] != 0;
  int t = threadIdx.x;
  float acc0 = 0.f, acc1 = 0.f;
  for (int b = 0; b < 64; b++) {
    acc0 += P[b * 256 + t];
    acc1 += P[(64 + b) * 256 + t];
  }
  v[t] = acc0 + acc1;
  __syncthreads();
  float acc = 0.f;
  if (f32) {
    const float* W3f = (const float*)W3;
    for (int f = 0; f < 256; f++) acc += v[f] * W3f[f * 256 + t];
    pooled[t] = acc * (1.0f / (2.0f * N_NODES)) + ((const float*)b3)[t];
  } else {
    const ushort* W3b = (const ushort*)W3;
    for (int f = 0; f < 256; f++) acc += v[f] * bf2f(W3b[f * 256 + t]);
    pooled[t] = acc * (1.0f / (2.0f * N_NODES)) + bf2f(((const ushort*)b3)[t]);
  }
  __syncthreads();
  if (t < 5) {
    float o;
    if (f32) {
      o = ((const float*)bl)[t];
      for (int h = 0; h < 256; h++) o += pooled[h] * ((const float*)Wl)[h * 5 + t];
      ((float*)out)[t] = o;
    } else {
      o = bf2f(((const ushort*)bl)[t]);
      for (int h = 0; h < 256; h++) o += pooled[h] * bf2f(((const ushort*)Wl)[h * 5 + t]);
      ((ushort*)out)[t] = f2bf(o);
    }
  }
}

extern "C" void kernel_launch(void* const* d_in, const int* in_sizes, int n_in,
                              void* d_out, int out_size, void* d_ws, size_t ws_size,
                              hipStream_t stream) {
  const void* x1 = d_in[0];
  const void* ei1 = d_in[1];
  const void* x2 = d_in[2];
  const void* ei2 = d_in[3];
  const void* W1 = d_in[4];
  const void* b1 = d_in[5];
  const void* W2 = d_in[6];
  const void* b2 = d_in[7];
  const void* W3 = d_in[8];
  const void* b3 = d_in[9];
  const void* Wl = d_in[10];
  const void* bl = d_in[11];

  char* p = (char*)d_ws;
  auto alloc = [&](size_t bytes) {
    char* r = p;
    p += (bytes + 255) & ~size_t(255);
    return r;
  };
  int* flags   = (int*)alloc(256);
  float* dinv0 = (float*)alloc(N_NODES * 4);
  float* dinv1 = (float*)alloc(N_NODES * 4);
  float* t0    = (float*)alloc(N_NODES * 4);
  float* t1    = (float*)alloc(N_NODES * 4);
  int* cnt0    = (int*)alloc(N_NODES * 4);
  int* cnt1    = (int*)alloc(N_NODES * 4);
  int* rp0     = (int*)alloc((N_NODES + 1) * 4);
  int* rp1     = (int*)alloc((N_NODES + 1) * 4);
  unsigned int* eg0 = (unsigned int*)alloc((size_t)N_EDGES * 4);
  unsigned int* eg1 = (unsigned int*)alloc((size_t)N_EDGES * 4);
  float* Pp    = (float*)alloc(2 * 64 * 256 * 4);
  ushort* wt1  = (ushort*)alloc(256 * 256 * 2);
  ushort* wt2  = (ushort*)alloc(256 * 256 * 2);
  ushort* xw0  = (ushort*)alloc((size_t)N_NODES * HID * 2);
  ushort* xw1  = (ushort*)alloc((size_t)N_NODES * HID * 2);
  ushort* h0   = (ushort*)alloc((size_t)N_NODES * HID * 2);
  ushort* h1   = (ushort*)alloc((size_t)N_NODES * HID * 2);
  // rank aliases h0 (NOT xw0: gemm1 runs concurrent with count/fill and
  // writes xw0/xw1). rank dead after fill; h0 first written by agg1.
  int* rank0  = (int*)h0;
  int* rank1  = rank0 + N_EDGES;

  // init+detect, wt
  init_detect_kernel<<<(N_NODES + 255) / 256 + 1, 256, 0, stream>>>(
      cnt0, cnt1, t0, t1, x1, ei1, flags);
  wt_kernel<<<512, 256, 0, stream>>>(W1, W2, wt1, wt2, flags);

  // OVERLAP 1: count_rank || gemm1-branch0  (825 blocks, one residency wave)
  countgemm_kernel<<<313 + 512, 512, 0, stream>>>(
      ei1, ei2, cnt0, cnt1, rank0, rank1, x1, wt1, xw0, flags);

  scan_kernel<<<2, 1024, 0, stream>>>(cnt0, cnt1, rp0, rp1, dinv0, dinv1);

  // OVERLAP 2: fill (eg-scatter + t) || gemm1-branch1
  fillgemm_kernel<<<313 + 1250 + 512, 512, 0, stream>>>(
      ei1, ei2, dinv0, dinv1, rp0, rp1, rank0, rank1, eg0, eg1, t0, t1,
      x2, wt1, xw1, flags);

  // Layer 1 aggregate: h = relu(agg(xw) + b1)
  agg_kernel<<<dim3(625, 2, 4), 256, 0, stream>>>(
      xw0, xw1, dinv0, dinv1, rp0, rp1, eg0, eg1, b1, h0, h1, flags);

  // Layer 2: xw = h @ W2 ; h = relu(agg(xw) + b2)
  gemm_kernel<<<dim3(625, 1, 2), 256, 0, stream>>>(h0, h1, wt2, xw0, xw1, 0, flags);
  agg_kernel<<<dim3(625, 2, 4), 256, 0, stream>>>(
      xw0, xw1, dinv0, dinv1, rp0, rp1, eg0, eg1, b2, h0, h1, flags);

  // Layer 3 + pool collapsed: s = sum_j c_j h2_j ; out = ((s0+s1)W3/(2N)+b3)@Wl+bl
  colsum_kernel<<<dim3(64, 2), 256, 0, stream>>>(h0, h1, dinv0, dinv1, t0, t1, Pp);
  final_kernel<<<1, 256, 0, stream>>>(Pp, W3, b3, Wl, bl, d_out, flags);
}